// Round 7
// baseline (942.340 us; speedup 1.0000x reference)
//
#include <hip/hip_runtime.h>
#include <cstddef>
#include <cstdint>

#define EPS_F 1e-7f
#define MAX_NORM_F 0.99999f   // (1 - 1e-5) / SC, SC = 1

typedef __attribute__((ext_vector_type(8))) short bf16x8;  // 8 bf16 (4 VGPR)
typedef __attribute__((ext_vector_type(4))) float f32x4;

// ---------------------------------------------------------------- helpers
__device__ __forceinline__ unsigned short f2bf(float x) {
  unsigned int u = __float_as_uint(x);
  unsigned int r = u + 0x7FFFu + ((u >> 16) & 1u);   // RNE (no NaN in data)
  return (unsigned short)(r >> 16);
}
__device__ __forceinline__ float bf2f(unsigned short h) {
  return __uint_as_float(((unsigned int)h) << 16);
}

__device__ __forceinline__ float wave_sum(float v) {
#pragma unroll
  for (int off = 32; off; off >>= 1) v += __shfl_xor(v, off);
  return v;
}

__device__ __forceinline__ void store_split4(unsigned short* H, unsigned short* L,
                                             size_t idx, float4 v) {
  ushort4 h, l;
  h.x = f2bf(v.x); l.x = f2bf(v.x - bf2f(h.x));
  h.y = f2bf(v.y); l.y = f2bf(v.y - bf2f(h.y));
  h.z = f2bf(v.z); l.z = f2bf(v.z - bf2f(h.z));
  h.w = f2bf(v.w); l.w = f2bf(v.w - bf2f(h.w));
  *reinterpret_cast<ushort4*>(H + idx) = h;
  *reinterpret_cast<ushort4*>(L + idx) = l;
}

// async global->LDS, 16B per lane; LDS dest = uniform base + lane*16
__device__ __forceinline__ void gl_lds16(const unsigned short* g, unsigned short* l) {
  __builtin_amdgcn_global_load_lds(
      (const __attribute__((address_space(1))) void*)g,
      (__attribute__((address_space(3))) void*)l, 16, 0, 0);
}

// fragment read offset (elements) for logical row r, k-group kg, tile base tb
__device__ __forceinline__ int frag_off(int tb, int r, int kg) {
  return tb + r * 32 + ((kg ^ ((r >> 1) & 3)) << 3);
}

// --------------------------------------------- weight transpose+split pass
struct WS4 {
  const float* W[4];
  unsigned short* Th[4];
  unsigned short* Tl[4];
  int K[4], N[4], Kp[4];
};

__global__ __launch_bounds__(256) void wsplit_all_k(WS4 d) {
  const int zi = blockIdx.z;
  const float* W = d.W[zi];
  unsigned short* Th = d.Th[zi];
  unsigned short* Tl = d.Tl[zi];
  const int K = d.K[zi], N = d.N[zi], Kp = d.Kp[zi];
  const int n0 = blockIdx.x * 64, k0 = blockIdx.y * 64;
  if (n0 >= N || k0 >= Kp) return;

  __shared__ float T[64][65];
  const int t = threadIdx.x;
  {
    const int lk = t >> 2;
    const int ln = (t & 3) * 16;
    const int gk = k0 + lk;
#pragma unroll
    for (int j = 0; j < 16; j += 4) {
      float4 v = make_float4(0.f, 0.f, 0.f, 0.f);
      const int gn = n0 + ln + j;
      if (gk < K) {
        if (gn + 3 < N) {
          v = *reinterpret_cast<const float4*>(W + (size_t)gk * N + gn);
        } else {
          const float* p = W + (size_t)gk * N;
          if (gn     < N) v.x = p[gn];
          if (gn + 1 < N) v.y = p[gn + 1];
          if (gn + 2 < N) v.z = p[gn + 2];
          if (gn + 3 < N) v.w = p[gn + 3];
        }
      }
      T[lk][ln + j + 0] = v.x; T[lk][ln + j + 1] = v.y;
      T[lk][ln + j + 2] = v.z; T[lk][ln + j + 3] = v.w;
    }
  }
  __syncthreads();
  {
    const int rn = t >> 2;
    const int rk = (t & 3) * 16;
    const int gn = n0 + rn;
    if (gn < N) {
      size_t base = (size_t)gn * Kp + k0 + rk;
#pragma unroll
      for (int j = 0; j < 16; ++j) {
        float x = T[rk + j][rn];
        unsigned short h = f2bf(x);
        unsigned short l = f2bf(x - bf2f(h));
        Th[base + j] = h;
        Tl[base + j] = l;
      }
    }
  }
}

// --------------------------------------------------------- bf16x3 MFMA GEMM
// acc += Ah*Bh + Ah*Bl + Al*Bh, 16x16x32 MFMA, PASS-MAJOR (independent MFMAs
// between reuses of the same acc). 64x64 tile, 4 waves (wave = 32x32),
// single-buffered 16KB LDS, XOR k-chunk swizzle (zero bank conflicts, r5).
// Out: fp32 C (optional split-K via blockIdx.z) OR split-bf16 Ch/Cl.
__global__ __launch_bounds__(256) void gemm64_x3(
    const unsigned short* __restrict__ Ah, const unsigned short* __restrict__ Al,
    int lda,
    const unsigned short* __restrict__ Bh, const unsigned short* __restrict__ Bl,
    int ldb,
    const float* __restrict__ bias, float* __restrict__ Cf,
    unsigned short* __restrict__ Ch, unsigned short* __restrict__ Cl,
    int ldc, int M, int N, int Ktot, int kslice, int relu)
{
  __shared__ unsigned short sm[8192];   // Ah@0 Al@2048 Bh@4096 Bl@6144

  const int t = threadIdx.x;
  const int bm = blockIdx.x * 64;
  const int bn = blockIdx.y * 64;
  const int z  = blockIdx.z;
  const int koff = z * kslice;
  const int klen = min(kslice, Ktot - koff);

  const int lane = t & 63, wave = t >> 6;
  const int wm = (wave >> 1) * 32, wn = (wave & 1) * 32;
  const int fr = lane & 15, kg = lane >> 4;

  // staging: 16 wave-issues (4 per tile); wave w takes j = w + 4q
  const unsigned short* sp[4];
  int dpo[4];
#pragma unroll
  for (int q = 0; q < 4; ++q) {
    const int j = wave + 4 * q;
    const int tile = j >> 2;            // 0 Ah, 1 Al, 2 Bh, 3 Bl
    const int i = j & 3;
    const int row = i * 16 + (lane >> 2);
    const int chunk = (lane & 3) ^ ((row >> 1) & 3);
    const unsigned short* base = (tile == 0) ? Ah : (tile == 1) ? Al
                               : (tile == 2) ? Bh : Bl;
    const int ld = (tile < 2) ? lda : ldb;
    const int grow = (tile < 2) ? (bm + row) : min(bn + row, N - 1);
    sp[q] = base + (size_t)grow * ld + koff + chunk * 8;
    dpo[q] = tile * 2048 + i * 512 + lane * 8;
  }

  int offA[2], offB[2];
#pragma unroll
  for (int i = 0; i < 2; ++i) {
    offA[i] = frag_off(0,    wm + i * 16 + fr, kg);
    offB[i] = frag_off(4096, wn + i * 16 + fr, kg);
  }

  f32x4 acc[2][2] = {};

  for (int k0 = 0; k0 < klen; k0 += 32) {
#pragma unroll
    for (int q = 0; q < 4; ++q) { gl_lds16(sp[q], sm + dpo[q]); sp[q] += 32; }
    __syncthreads();

    bf16x8 ah[2], al[2], bh[2], bl[2];
#pragma unroll
    for (int i = 0; i < 2; ++i) {
      ah[i] = *reinterpret_cast<const bf16x8*>(sm + offA[i]);
      al[i] = *reinterpret_cast<const bf16x8*>(sm + offA[i] + 2048);
      bh[i] = *reinterpret_cast<const bf16x8*>(sm + offB[i]);
      bl[i] = *reinterpret_cast<const bf16x8*>(sm + offB[i] + 2048);
    }
    // pass-major: 4 independent MFMAs per pass
#pragma unroll
    for (int mi = 0; mi < 2; ++mi)
#pragma unroll
      for (int ni = 0; ni < 2; ++ni)
        acc[mi][ni] = __builtin_amdgcn_mfma_f32_16x16x32_bf16(ah[mi], bh[ni], acc[mi][ni], 0, 0, 0);
#pragma unroll
    for (int mi = 0; mi < 2; ++mi)
#pragma unroll
      for (int ni = 0; ni < 2; ++ni)
        acc[mi][ni] = __builtin_amdgcn_mfma_f32_16x16x32_bf16(ah[mi], bl[ni], acc[mi][ni], 0, 0, 0);
#pragma unroll
    for (int mi = 0; mi < 2; ++mi)
#pragma unroll
      for (int ni = 0; ni < 2; ++ni)
        acc[mi][ni] = __builtin_amdgcn_mfma_f32_16x16x32_bf16(al[mi], bh[ni], acc[mi][ni], 0, 0, 0);
    __syncthreads();
  }

#pragma unroll
  for (int mi = 0; mi < 2; ++mi) {
#pragma unroll
    for (int ni = 0; ni < 2; ++ni) {
      const int col = bn + wn + ni * 16 + fr;
      if (col >= N) continue;
      const int row0 = bm + wm + mi * 16 + kg * 4;
      const float bv = bias ? bias[col] : 0.f;
      if (Cf) {
        float* Cz = Cf + (size_t)z * (size_t)M * (size_t)N;
#pragma unroll
        for (int r = 0; r < 4; ++r) {
          float v = acc[mi][ni][r] + bv;
          if (relu) v = fmaxf(v, 0.f);
          Cz[(size_t)(row0 + r) * ldc + col] = v;
        }
      } else {
#pragma unroll
        for (int r = 0; r < 4; ++r) {
          float v = acc[mi][ni][r] + bv;
          if (relu) v = fmaxf(v, 0.f);
          const size_t o = (size_t)(row0 + r) * ldc + col;
          unsigned short h = f2bf(v);
          Ch[o] = h;
          Cl[o] = f2bf(v - bf2f(h));
        }
      }
    }
  }
}

// ---- embed GEMM: x2 (Ah*Bh + Ah*Bl; A-lo dropped — error << threshold).
// 128x64 tile, fp32 A reg-staged + converted, B via gl_lds. 16KB LDS sbuf.
// grid (120, 4, 4): M=15360, N=256 (4 bn tiles), z = component.
__global__ __launch_bounds__(256) void gemm_embed_x2(
    const float* __restrict__ A0, const float* __restrict__ A1,
    const float* __restrict__ A2, const float* __restrict__ A3,
    const unsigned short* __restrict__ EW, const float* __restrict__ b_embed,
    float* __restrict__ TAN)
{
  __shared__ unsigned short sm[8192];   // Ah@0 (128x32) Bh@4096 Bl@6144

  const int c = blockIdx.z;
  const float* A = (c == 0) ? A0 : (c == 1) ? A1 : (c == 2) ? A2 : A3;
  const unsigned short* Bh = EW + (size_t)c * 262144u;
  const unsigned short* Bl = Bh + 131072u;
  const float* bias = b_embed + c * 256;
  float* C = TAN + (size_t)c * 15360 * 256;

  const int t = threadIdx.x;
  const int bm = blockIdx.x * 128;
  const int bn = blockIdx.y * 64;
  const int lane = t & 63, wave = t >> 6;
  const int wm = (wave >> 1) * 64, wn = (wave & 1) * 32;
  const int fr = lane & 15, kg = lane >> 4;

  // B staging: 8 wave-issues; wave w: j = w + 4q, q=0..1
  const unsigned short* sp[2];
  int dpo[2];
#pragma unroll
  for (int q = 0; q < 2; ++q) {
    const int j = wave + 4 * q;
    const int tile = j >> 2;            // 0 Bh, 1 Bl
    const int i = j & 3;
    const int row = i * 16 + (lane >> 2);
    const int chunk = (lane & 3) ^ ((row >> 1) & 3);
    const unsigned short* base = tile ? Bl : Bh;
    sp[q] = base + (size_t)(bn + row) * 512 + chunk * 8;
    dpo[q] = 4096 + tile * 2048 + i * 512 + lane * 8;
  }

  // A staging: thread t -> row t>>1, khalf t&1 (16 fp32 -> 16 bf16 hi)
  const int arow = t >> 1, khalf = t & 1;
  const float* aptr = A + (size_t)(bm + arow) * 504 + khalf * 16;
  const int axor = (arow >> 1) & 3;
  const int woff0 = arow * 32 + (((khalf * 2)     ^ axor) << 3);
  const int woff1 = arow * 32 + (((khalf * 2 + 1) ^ axor) << 3);

  int offA[4], offB[2];
#pragma unroll
  for (int i = 0; i < 4; ++i) offA[i] = frag_off(0, wm + i * 16 + fr, kg);
#pragma unroll
  for (int i = 0; i < 2; ++i) offB[i] = frag_off(4096, wn + i * 16 + fr, kg);

  float4 fa0, fa1, fa2, fa3;
  const float4 zf = make_float4(0.f, 0.f, 0.f, 0.f);
  auto loadA = [&](int k0) {
    const int gk = k0 + khalf * 16;
    fa0 = (gk      < 504) ? *reinterpret_cast<const float4*>(aptr + k0)      : zf;
    fa1 = (gk + 4  < 504) ? *reinterpret_cast<const float4*>(aptr + k0 + 4)  : zf;
    fa2 = (gk + 8  < 504) ? *reinterpret_cast<const float4*>(aptr + k0 + 8)  : zf;
    fa3 = (gk + 12 < 504) ? *reinterpret_cast<const float4*>(aptr + k0 + 12) : zf;
  };

  f32x4 acc[4][2] = {};
  loadA(0);

  for (int k0 = 0; k0 < 512; k0 += 32) {
    {  // convert prefetched A regs -> bf16 hi -> LDS
      float xs[16] = {fa0.x, fa0.y, fa0.z, fa0.w, fa1.x, fa1.y, fa1.z, fa1.w,
                      fa2.x, fa2.y, fa2.z, fa2.w, fa3.x, fa3.y, fa3.z, fa3.w};
      bf16x8 p;
#pragma unroll
      for (int i = 0; i < 8; ++i) p[i] = (short)f2bf(xs[i]);
      *reinterpret_cast<bf16x8*>(sm + woff0) = p;
#pragma unroll
      for (int i = 0; i < 8; ++i) p[i] = (short)f2bf(xs[8 + i]);
      *reinterpret_cast<bf16x8*>(sm + woff1) = p;
    }
#pragma unroll
    for (int q = 0; q < 2; ++q) { gl_lds16(sp[q], sm + dpo[q]); sp[q] += 32; }
    __syncthreads();                     // A writes + B gl_lds complete
    if (k0 + 32 < 512) loadA(k0 + 32);   // reg prefetch next A (covered by MFMA)

    bf16x8 ah[4], bh[2], bl[2];
#pragma unroll
    for (int i = 0; i < 4; ++i)
      ah[i] = *reinterpret_cast<const bf16x8*>(sm + offA[i]);
#pragma unroll
    for (int i = 0; i < 2; ++i) {
      bh[i] = *reinterpret_cast<const bf16x8*>(sm + offB[i]);
      bl[i] = *reinterpret_cast<const bf16x8*>(sm + offB[i] + 2048);
    }
    // pass-major: 8 independent per pass
#pragma unroll
    for (int mi = 0; mi < 4; ++mi)
#pragma unroll
      for (int ni = 0; ni < 2; ++ni)
        acc[mi][ni] = __builtin_amdgcn_mfma_f32_16x16x32_bf16(ah[mi], bh[ni], acc[mi][ni], 0, 0, 0);
#pragma unroll
    for (int mi = 0; mi < 4; ++mi)
#pragma unroll
      for (int ni = 0; ni < 2; ++ni)
        acc[mi][ni] = __builtin_amdgcn_mfma_f32_16x16x32_bf16(ah[mi], bl[ni], acc[mi][ni], 0, 0, 0);
    __syncthreads();
  }

#pragma unroll
  for (int mi = 0; mi < 4; ++mi) {
#pragma unroll
    for (int ni = 0; ni < 2; ++ni) {
      const int col = bn + wn + ni * 16 + fr;
      const int row0 = bm + wm + mi * 16 + kg * 4;
      const float bv = bias[col];
#pragma unroll
      for (int r = 0; r < 4; ++r)
        C[(size_t)(row0 + r) * 256 + col] = acc[mi][ni][r] + bv;
    }
  }
}

// ------------------------------------- LayerNorm + expmap0 -> Z (wave/row)
__global__ __launch_bounds__(256) void ln_expmap0_k(
    const float* __restrict__ TAN, const float* __restrict__ gamma,
    const float* __restrict__ beta, float* __restrict__ Z)
{
  const int row = blockIdx.x * 4 + (threadIdx.x >> 6);   // b*30 + n
  const int lane = threadIdx.x & 63;
  const int b = row / 30;
  const int n = row % 30;

  float4 tc[4];
  float4 ts = make_float4(0.f, 0.f, 0.f, 0.f);
#pragma unroll
  for (int c = 0; c < 4; ++c) {
    float4 x = *reinterpret_cast<const float4*>(
        TAN + ((size_t)c * 15360 + row) * 256 + lane * 4);
    float mu = wave_sum(x.x + x.y + x.z + x.w) * (1.f / 256.f);
    float4 xm = make_float4(x.x - mu, x.y - mu, x.z - mu, x.w - mu);
    float var = wave_sum(xm.x * xm.x + xm.y * xm.y + xm.z * xm.z + xm.w * xm.w)
                * (1.f / 256.f);
    float rs = rsqrtf(var + 1e-5f);
    float4 g = *reinterpret_cast<const float4*>(gamma + c * 256 + lane * 4);
    float4 be = *reinterpret_cast<const float4*>(beta + c * 256 + lane * 4);
    float4 tv = make_float4(xm.x * rs * g.x + be.x, xm.y * rs * g.y + be.y,
                            xm.z * rs * g.z + be.z, xm.w * rs * g.w + be.w);
    tc[c] = tv;
    ts.x += tv.x; ts.y += tv.y; ts.z += tv.z; ts.w += tv.w;
  }
#pragma unroll
  for (int g5 = 0; g5 < 5; ++g5) {
    float4 v = (g5 == 0) ? ts : tc[g5 - 1];
    float n2 = wave_sum(v.x * v.x + v.y * v.y + v.z * v.z + v.w * v.w);
    float nn = fmaxf(sqrtf(n2), EPS_F);
    float th = tanhf(nn);
    float w = th / nn;
    if (th > MAX_NORM_F) w *= MAX_NORM_F / fmaxf(th, EPS_F);
    float4 o = make_float4(v.x * w, v.y * w, v.z * w, v.w * w);
    *reinterpret_cast<float4*>(
        Z + (((size_t)g5 * 512 + b) * 38 + n) * 256 + lane * 4) = o;
  }
}

// ------------------------------------------------ per-pair logmap (1 wave)
__device__ __forceinline__ float4 pair_log(const float* zr, int c, int lane) {
  float4 x = *reinterpret_cast<const float4*>(zr + (size_t)c * 256 + lane * 4);
  float4 y = *reinterpret_cast<const float4*>(zr + (size_t)(c + 1) * 256 + lane * 4);
  float x2 = wave_sum(x.x * x.x + x.y * x.y + x.z * x.z + x.w * x.w);
  float y2 = wave_sum(y.x * y.x + y.y * y.y + y.z * y.z + y.w * y.w);
  float xy = wave_sum(x.x * y.x + x.y * y.y + x.z * y.z + x.w * y.w);
  float a  = 1.f - 2.f * xy + y2;
  float bb = 1.f - x2;
  float den = fmaxf(1.f - 2.f * xy + x2 * y2, EPS_F);
  float inv = 1.f / den;
  float4 u;
  u.x = (bb * y.x - a * x.x) * inv;
  u.y = (bb * y.y - a * x.y) * inv;
  u.z = (bb * y.z - a * x.z) * inv;
  u.w = (bb * y.w - a * x.w) * inv;
  float u2 = wave_sum(u.x * u.x + u.y * u.y + u.z * u.z + u.w * u.w);
  float un = fmaxf(sqrtf(u2), EPS_F);
  float coef = fmaxf(1.f - x2, EPS_F) * atanhf(fminf(un, 1.f - 1e-7f)) / un;
  float4 o;
  o.x = coef * u.x; o.y = coef * u.y; o.z = coef * u.z; o.w = coef * u.w;
  return o;
}

__device__ __forceinline__ float4 logmap0_col(const float* zr, int c, int lane) {
  float4 z = *reinterpret_cast<const float4*>(zr + (size_t)c * 256 + lane * 4);
  float z2 = wave_sum(z.x * z.x + z.y * z.y + z.z * z.z + z.w * z.w);
  float nz = fmaxf(sqrtf(z2), EPS_F);
  float cc = atanhf(fminf(nz, 1.f - 1e-7f)) / nz;
  float4 o;
  o.x = cc * z.x; o.y = cc * z.y; o.z = cc * z.z; o.w = cc * z.w;
  return o;
}

// -------------------------- velocity (t=0 full window) + feat
__global__ __launch_bounds__(256) void vel_feat_inc_k(
    const float* __restrict__ Z, unsigned short* __restrict__ Fh,
    unsigned short* __restrict__ Fl, float* __restrict__ VSUM, int t)
{
  const int r = blockIdx.x * 4 + (threadIdx.x >> 6);
  const int lane = threadIdx.x & 63;
  const float* zr = Z + (size_t)r * 38 * 256;

  float4 vs = make_float4(0.f, 0.f, 0.f, 0.f);
#pragma unroll 1
  for (int j = 0; j < 29; ++j) {
    float4 p = pair_log(zr, t + j, lane);
    vs.x += p.x; vs.y += p.y; vs.z += p.z; vs.w += p.w;
  }
  *reinterpret_cast<float4*>(VSUM + (size_t)r * 256 + lane * 4) = vs;

  float4 fl = logmap0_col(zr, t + 29, lane);   // z_last
  float4 fp = logmap0_col(zr, t + 28, lane);   // z_prev
  const size_t fb = (size_t)r * 768 + lane * 4;
  store_split4(Fh, Fl, fb, fl);
  store_split4(Fh, Fl, fb + 256, fp);
  const float s29 = 1.f / 29.f;
  float4 o;
  o.x = vs.x * s29; o.y = vs.y * s29; o.z = vs.z * s29; o.w = vs.w * s29;
  store_split4(Fh, Fl, fb + 512, o);
}

// --------- fused: z_next = expmap(z_last, sum VP + b3); then (if t<7)
// incremental velocity + FEAT for step t+1 (z_next, z_last in registers).
__global__ __launch_bounds__(256) void expmap_vel_fused_k(
    float* __restrict__ Z, const float* __restrict__ VP,
    const float* __restrict__ b3, unsigned short* __restrict__ Fh,
    unsigned short* __restrict__ Fl, float* __restrict__ VSUM, int t)
{
  const int r = blockIdx.x * 4 + (threadIdx.x >> 6);
  const int lane = threadIdx.x & 63;
  float* zr = Z + (size_t)r * 38 * 256;
  float4 x = *reinterpret_cast<const float4*>(zr + (size_t)(t + 29) * 256 + lane * 4);
  float4 v = *reinterpret_cast<const float4*>(b3 + lane * 4);
#pragma unroll
  for (int p = 0; p < 8; ++p) {
    float4 a = *reinterpret_cast<const float4*>(
        VP + (size_t)p * 655360u + (size_t)r * 256 + lane * 4);
    v.x += a.x; v.y += a.y; v.z += a.z; v.w += a.w;
  }
  float x2 = wave_sum(x.x * x.x + x.y * x.y + x.z * x.z + x.w * x.w);
  float v2 = wave_sum(v.x * v.x + v.y * v.y + v.z * v.z + v.w * v.w);
  float xv = wave_sum(x.x * v.x + x.y * v.y + x.z * v.z + x.w * v.w);

  float vn = fmaxf(sqrtf(v2), EPS_F);
  float lamx = 2.f / fmaxf(1.f - x2, EPS_F);
  float s = tanhf(0.5f * lamx * vn) / vn;
  float xy = s * xv;
  float y2 = s * s * v2;
  float a  = 1.f + 2.f * xy + y2;
  float bb = 1.f - x2;
  float den = fmaxf(1.f + 2.f * xy + x2 * y2, EPS_F);
  float inv = 1.f / den;
  float4 res;
  res.x = (a * x.x + bb * s * v.x) * inv;
  res.y = (a * x.y + bb * s * v.y) * inv;
  res.z = (a * x.z + bb * s * v.z) * inv;
  res.w = (a * x.w + bb * s * v.w) * inv;
  float r2 = wave_sum(res.x * res.x + res.y * res.y + res.z * res.z + res.w * res.w);
  float rn = sqrtf(r2);
  if (rn > MAX_NORM_F) {
    float sc = MAX_NORM_F / fmaxf(rn, EPS_F);
    res.x *= sc; res.y *= sc; res.z *= sc; res.w *= sc;
    r2 = MAX_NORM_F * MAX_NORM_F;
    rn = MAX_NORM_F;
  }
  *reinterpret_cast<float4*>(zr + (size_t)(t + 30) * 256 + lane * 4) = res;

  if (t < 7) {
    float4 pm = pair_log(zr, t, lane);
    float xyn = wave_sum(x.x * res.x + x.y * res.y + x.z * res.z + x.w * res.w);
    float an  = 1.f - 2.f * xyn + r2;
    float bbn = 1.f - x2;
    float denn = fmaxf(1.f - 2.f * xyn + x2 * r2, EPS_F);
    float invn = 1.f / denn;
    float4 u;
    u.x = (bbn * res.x - an * x.x) * invn;
    u.y = (bbn * res.y - an * x.y) * invn;
    u.z = (bbn * res.z - an * x.z) * invn;
    u.w = (bbn * res.w - an * x.w) * invn;
    float u2 = wave_sum(u.x * u.x + u.y * u.y + u.z * u.z + u.w * u.w);
    float un = fmaxf(sqrtf(u2), EPS_F);
    float coef = fmaxf(1.f - x2, EPS_F) * atanhf(fminf(un, 1.f - 1e-7f)) / un;
    float4 vs = *reinterpret_cast<const float4*>(VSUM + (size_t)r * 256 + lane * 4);
    vs.x += coef * u.x - pm.x; vs.y += coef * u.y - pm.y;
    vs.z += coef * u.z - pm.z; vs.w += coef * u.w - pm.w;
    *reinterpret_cast<float4*>(VSUM + (size_t)r * 256 + lane * 4) = vs;

    float rnp = fmaxf(rn, EPS_F);
    float cl = atanhf(fminf(rnp, 1.f - 1e-7f)) / rnp;
    float nx = fmaxf(sqrtf(x2), EPS_F);
    float cp = atanhf(fminf(nx, 1.f - 1e-7f)) / nx;
    const size_t fb = (size_t)r * 768 + lane * 4;
    float4 o;
    o.x = cl * res.x; o.y = cl * res.y; o.z = cl * res.z; o.w = cl * res.w;
    store_split4(Fh, Fl, fb, o);
    o.x = cp * x.x; o.y = cp * x.y; o.z = cp * x.z; o.w = cp * x.w;
    store_split4(Fh, Fl, fb + 256, o);
    const float s29 = 1.f / 29.f;
    o.x = vs.x * s29; o.y = vs.y * s29; o.z = vs.z * s29; o.w = vs.w * s29;
    store_split4(Fh, Fl, fb + 512, o);
  }
}

// -------------------------- logmap0 over appended cols, split bf16 out
__global__ __launch_bounds__(256) void logmap0_rows_k(
    const float* __restrict__ Z, unsigned short* __restrict__ Uh,
    unsigned short* __restrict__ Ul)
{
  const int q = blockIdx.x * 4 + (threadIdx.x >> 6);
  const int lane = threadIdx.x & 63;
  const int r = q >> 3;
  const int tt = q & 7;
  float4 o = logmap0_col(Z + (size_t)r * 38 * 256, 30 + tt, lane);
  store_split4(Uh, Ul, (size_t)q * 256 + lane * 4, o);
}

// ---------------------------------------------------------------- launcher
extern "C" void kernel_launch(void* const* d_in, const int* in_sizes, int n_in,
                              void* d_out, int out_size, void* d_ws, size_t ws_size,
                              hipStream_t stream)
{
  const float* c0 = (const float*)d_in[0];
  const float* c1 = (const float*)d_in[1];
  const float* c2 = (const float*)d_in[2];
  const float* c3 = (const float*)d_in[3];
  const float* W_embed = (const float*)d_in[4];
  const float* b_embed = (const float*)d_in[5];
  const float* ln_g    = (const float*)d_in[6];
  const float* ln_b    = (const float*)d_in[7];
  const float* W1 = (const float*)d_in[8];
  const float* b1 = (const float*)d_in[9];
  const float* W2 = (const float*)d_in[10];
  const float* b2 = (const float*)d_in[11];
  const float* W3 = (const float*)d_in[12];
  const float* b3 = (const float*)d_in[13];
  const float* W_out = (const float*)d_in[14];
  const float* b_out = (const float*)d_in[15];
  float* out = (float*)d_out;
  float* ws  = (float*)d_ws;

  // ---- ws layout (floats). Peak = Z(24,903,680) + R(15,728,640) = 162.5 MB.
  float* Z = ws;
  float* TAN = ws + 24903680u;                      // R region = TAN in stage A
  unsigned short* Rs = (unsigned short*)(ws + 24903680u);
  unsigned short* W1h = Rs;                         // [1024][768]
  unsigned short* W1l = Rs + 786432u;
  unsigned short* W2h = Rs + 1572864u;              // [1024][1024]
  unsigned short* W2l = Rs + 2621440u;
  unsigned short* W3h = Rs + 3670016u;              // [256][1024]
  unsigned short* W3l = Rs + 3932160u;
  unsigned short* Woh = Rs + 4194304u;              // [504][256]
  unsigned short* Wol = Rs + 4323328u;
  unsigned short* FEATh = Rs + 4452352u;            // [2560][768]
  unsigned short* FEATl = Rs + 6418432u;
  unsigned short* H1h = Rs + 8384512u;              // [2560][1024]
  unsigned short* H1l = Rs + 11005952u;
  unsigned short* H2h = Rs + 13627392u;             // [2560][1024]
  unsigned short* H2l = Rs + 16248832u;             // ends @ short 18,870,272
  float* VP   = ws + 34338816u;                     // 8 x 2560*256 parts
  float* VSUM = ws + 39581696u;                     // 2560*256
  unsigned short* Uh = Rs + 4452352u;               // stage C, reuses FEAT/H1
  unsigned short* Ul = Rs + 9695232u;

  // ---- d_out scratch: embed weights (stage A only; final GEMM overwrites).
  unsigned short* EW = (unsigned short*)d_out;      // 4 x (h 131072 | l 131072)

  dim3 blk(256);

  // Stage A: embed weight split -> embed GEMM (x2) -> LN+expmap0
  {
    WS4 d;
    for (int c = 0; c < 4; ++c) {
      d.W[c] = W_embed + (size_t)c * 504 * 256;
      d.Th[c] = EW + (size_t)c * 262144u;
      d.Tl[c] = EW + (size_t)c * 262144u + 131072u;
      d.K[c] = 504; d.N[c] = 256; d.Kp[c] = 512;
    }
    wsplit_all_k<<<dim3(4, 8, 4), blk, 0, stream>>>(d);
  }
  gemm_embed_x2<<<dim3(120, 4, 4), blk, 0, stream>>>(
      c0, c1, c2, c3, EW, b_embed, TAN);
  ln_expmap0_k<<<dim3(3840), blk, 0, stream>>>(TAN, ln_g, ln_b, Z);

  // MLP/out weight splits in one launch (TAN dead now)
  {
    WS4 d;
    d.W[0] = W1;    d.Th[0] = W1h; d.Tl[0] = W1l; d.K[0] = 768;  d.N[0] = 1024; d.Kp[0] = 768;
    d.W[1] = W2;    d.Th[1] = W2h; d.Tl[1] = W2l; d.K[1] = 1024; d.N[1] = 1024; d.Kp[1] = 1024;
    d.W[2] = W3;    d.Th[2] = W3h; d.Tl[2] = W3l; d.K[2] = 1024; d.N[2] = 256;  d.Kp[2] = 1024;
    d.W[3] = W_out; d.Th[3] = Woh; d.Tl[3] = Wol; d.K[3] = 256;  d.N[3] = 504;  d.Kp[3] = 256;
    wsplit_all_k<<<dim3(16, 16, 4), blk, 0, stream>>>(d);
  }

  // Stage B: 8 recurrent steps (velocity/feat fused into expmap)
  vel_feat_inc_k<<<dim3(640), blk, 0, stream>>>(Z, FEATh, FEATl, VSUM, 0);
  for (int t = 0; t < 8; ++t) {
    gemm64_x3<<<dim3(40, 16, 1), blk, 0, stream>>>(
        FEATh, FEATl, 768, W1h, W1l, 768, b1,
        nullptr, H1h, H1l, 1024, 2560, 1024, 768, 768, 1);
    gemm64_x3<<<dim3(40, 16, 1), blk, 0, stream>>>(
        H1h, H1l, 1024, W2h, W2l, 1024, b2,
        nullptr, H2h, H2l, 1024, 2560, 1024, 1024, 1024, 1);
    gemm64_x3<<<dim3(40, 4, 8), blk, 0, stream>>>(
        H2h, H2l, 1024, W3h, W3l, 1024, nullptr,
        VP, nullptr, nullptr, 256, 2560, 256, 1024, 128, 0);
    expmap_vel_fused_k<<<dim3(640), blk, 0, stream>>>(
        Z, VP, b3, FEATh, FEATl, VSUM, t);
  }

  // Stage C: logmap0 -> final projection into d_out
  logmap0_rows_k<<<dim3(5120), blk, 0, stream>>>(Z, Uh, Ul);
  gemm64_x3<<<dim3(320, 8, 1), blk, 0, stream>>>(
      Uh, Ul, 256, Woh, Wol, 256, b_out,
      out, nullptr, nullptr, 504, 20480, 504, 256, 256, 0);
}

// Round 8
// 718.714 us; speedup vs baseline: 1.3111x; 1.3111x over previous
//
#include <hip/hip_runtime.h>
#include <cstddef>
#include <cstdint>

#define EPS_F 1e-7f
#define MAX_NORM_F 0.99999f   // (1 - 1e-5) / SC, SC = 1

typedef __attribute__((ext_vector_type(8))) short bf16x8;  // 8 bf16 (4 VGPR)
typedef __attribute__((ext_vector_type(4))) float f32x4;

// ---------------------------------------------------------------- helpers
__device__ __forceinline__ unsigned short f2bf(float x) {
  unsigned int u = __float_as_uint(x);
  unsigned int r = u + 0x7FFFu + ((u >> 16) & 1u);   // RNE (no NaN in data)
  return (unsigned short)(r >> 16);
}
__device__ __forceinline__ float bf2f(unsigned short h) {
  return __uint_as_float(((unsigned int)h) << 16);
}

__device__ __forceinline__ float wave_sum(float v) {
#pragma unroll
  for (int off = 32; off; off >>= 1) v += __shfl_xor(v, off);
  return v;
}

__device__ __forceinline__ void store_hi4(unsigned short* H, size_t idx, float4 v) {
  ushort4 h;
  h.x = f2bf(v.x); h.y = f2bf(v.y); h.z = f2bf(v.z); h.w = f2bf(v.w);
  *reinterpret_cast<ushort4*>(H + idx) = h;
}

// async global->LDS, 16B per lane; LDS dest = uniform base + lane*16
__device__ __forceinline__ void gl_lds16(const unsigned short* g, unsigned short* l) {
  __builtin_amdgcn_global_load_lds(
      (const __attribute__((address_space(1))) void*)g,
      (__attribute__((address_space(3))) void*)l, 16, 0, 0);
}

// fragment read offset (elements) for logical row r, k-group kg, tile base tb
__device__ __forceinline__ int frag_off(int tb, int r, int kg) {
  return tb + r * 32 + ((kg ^ ((r >> 1) & 3)) << 3);
}

// --------------------------------------------- weight transpose+split pass
struct WS4 {
  const float* W[4];
  unsigned short* Th[4];
  unsigned short* Tl[4];
  int K[4], N[4], Kp[4];
};

__global__ __launch_bounds__(256) void wsplit_all_k(WS4 d) {
  const int zi = blockIdx.z;
  const float* W = d.W[zi];
  unsigned short* Th = d.Th[zi];
  unsigned short* Tl = d.Tl[zi];
  const int K = d.K[zi], N = d.N[zi], Kp = d.Kp[zi];
  const int n0 = blockIdx.x * 64, k0 = blockIdx.y * 64;
  if (n0 >= N || k0 >= Kp) return;

  __shared__ float T[64][65];
  const int t = threadIdx.x;
  {
    const int lk = t >> 2;
    const int ln = (t & 3) * 16;
    const int gk = k0 + lk;
#pragma unroll
    for (int j = 0; j < 16; j += 4) {
      float4 v = make_float4(0.f, 0.f, 0.f, 0.f);
      const int gn = n0 + ln + j;
      if (gk < K) {
        if (gn + 3 < N) {
          v = *reinterpret_cast<const float4*>(W + (size_t)gk * N + gn);
        } else {
          const float* p = W + (size_t)gk * N;
          if (gn     < N) v.x = p[gn];
          if (gn + 1 < N) v.y = p[gn + 1];
          if (gn + 2 < N) v.z = p[gn + 2];
          if (gn + 3 < N) v.w = p[gn + 3];
        }
      }
      T[lk][ln + j + 0] = v.x; T[lk][ln + j + 1] = v.y;
      T[lk][ln + j + 2] = v.z; T[lk][ln + j + 3] = v.w;
    }
  }
  __syncthreads();
  {
    const int rn = t >> 2;
    const int rk = (t & 3) * 16;
    const int gn = n0 + rn;
    if (gn < N) {
      size_t base = (size_t)gn * Kp + k0 + rk;
#pragma unroll
      for (int j = 0; j < 16; ++j) {
        float x = T[rk + j][rn];
        unsigned short h = f2bf(x);
        unsigned short l = f2bf(x - bf2f(h));
        Th[base + j] = h;
        Tl[base + j] = l;
      }
    }
  }
}

// --------------------------------------------------- MLP GEMM: x2, 128x64
// acc += Ah*Bh + Ah*Bl (A = bf16-hi activations; B = split weights).
// gl_lds staging, double-buffered 32KB LDS, 1 barrier/iter, prefetch-early.
// Output: fp32 C (split-K via blockIdx.z) if Cf, else bf16-hi Ch.
__global__ __launch_bounds__(256) void gemm_n64_x2(
    const unsigned short* __restrict__ Ah, int lda,
    const unsigned short* __restrict__ Bh, const unsigned short* __restrict__ Bl,
    int ldb,
    const float* __restrict__ bias, float* __restrict__ Cf,
    unsigned short* __restrict__ Ch,
    int ldc, int M, int N, int Ktot, int kslice, int relu)
{
  __shared__ unsigned short sm[16384];   // 2 x (Ah@0 Bh@4096 Bl@6144)

  const int t = threadIdx.x;
  const int bm = blockIdx.x * 128;
  const int bn = blockIdx.y * 64;
  const int z  = blockIdx.z;
  const int koff = z * kslice;
  const int klen = min(kslice, Ktot - koff);

  const int lane = t & 63, wave = t >> 6;
  const int wm = (wave >> 1) * 64, wn = (wave & 1) * 32;
  const int fr = lane & 15, kg = lane >> 4;

  // 16 wave-issues: j<8 Ah(i=j), j<12 Bh(i=j-8), j<16 Bl(i=j-12)
  const unsigned short* sp[4];
  int dpo[4];
#pragma unroll
  for (int q = 0; q < 4; ++q) {
    const int j = wave + 4 * q;
    int tile, i;
    if (j < 8)       { tile = 0; i = j; }
    else if (j < 12) { tile = 1; i = j - 8; }
    else             { tile = 2; i = j - 12; }
    const int row = i * 16 + (lane >> 2);
    const int chunk = (lane & 3) ^ ((row >> 1) & 3);
    const unsigned short* base = (tile == 0) ? Ah : (tile == 1) ? Bh : Bl;
    const int ld = (tile == 0) ? lda : ldb;
    const int grow = (tile == 0) ? (bm + row) : min(bn + row, N - 1);
    const int tb = (tile == 0) ? 0 : (tile == 1) ? 4096 : 6144;
    sp[q] = base + (size_t)grow * ld + koff + chunk * 8;
    dpo[q] = tb + i * 512 + lane * 8;
  }

  int offA[4], offB[2];
#pragma unroll
  for (int i = 0; i < 4; ++i) offA[i] = frag_off(0, wm + i * 16 + fr, kg);
#pragma unroll
  for (int i = 0; i < 2; ++i) offB[i] = frag_off(4096, wn + i * 16 + fr, kg);

  f32x4 acc[4][2] = {};
#pragma unroll
  for (int q = 0; q < 4; ++q) gl_lds16(sp[q], sm + dpo[q]);

  int cur = 0;
  for (int k0 = 0; k0 < klen; k0 += 32) {
    __syncthreads();                     // buf[cur] staged
    if (k0 + 32 < klen) {
      unsigned short* nb = sm + (cur ^ 1) * 8192;
#pragma unroll
      for (int q = 0; q < 4; ++q) { sp[q] += 32; gl_lds16(sp[q], nb + dpo[q]); }
    }
    const unsigned short* s = sm + cur * 8192;
    bf16x8 ah[4], bh[2], bl[2];
#pragma unroll
    for (int i = 0; i < 4; ++i)
      ah[i] = *reinterpret_cast<const bf16x8*>(s + offA[i]);
#pragma unroll
    for (int i = 0; i < 2; ++i) {
      bh[i] = *reinterpret_cast<const bf16x8*>(s + offB[i]);
      bl[i] = *reinterpret_cast<const bf16x8*>(s + offB[i] + 2048);
    }
    // pass-major
#pragma unroll
    for (int mi = 0; mi < 4; ++mi)
#pragma unroll
      for (int ni = 0; ni < 2; ++ni)
        acc[mi][ni] = __builtin_amdgcn_mfma_f32_16x16x32_bf16(ah[mi], bh[ni], acc[mi][ni], 0, 0, 0);
#pragma unroll
    for (int mi = 0; mi < 4; ++mi)
#pragma unroll
      for (int ni = 0; ni < 2; ++ni)
        acc[mi][ni] = __builtin_amdgcn_mfma_f32_16x16x32_bf16(ah[mi], bl[ni], acc[mi][ni], 0, 0, 0);
    cur ^= 1;
  }

#pragma unroll
  for (int mi = 0; mi < 4; ++mi) {
#pragma unroll
    for (int ni = 0; ni < 2; ++ni) {
      const int col = bn + wn + ni * 16 + fr;
      if (col >= N) continue;
      const int row0 = bm + wm + mi * 16 + kg * 4;
      const float bv = bias ? bias[col] : 0.f;
      if (Cf) {
        float* Cz = Cf + (size_t)z * (size_t)M * (size_t)N;
#pragma unroll
        for (int r = 0; r < 4; ++r) {
          float v = acc[mi][ni][r] + bv;
          if (relu) v = fmaxf(v, 0.f);
          Cz[(size_t)(row0 + r) * ldc + col] = v;
        }
      } else {
#pragma unroll
        for (int r = 0; r < 4; ++r) {
          float v = acc[mi][ni][r] + bv;
          if (relu) v = fmaxf(v, 0.f);
          Ch[(size_t)(row0 + r) * ldc + col] = f2bf(v);
        }
      }
    }
  }
}

// ---- embed GEMM: x2 (Ah*Bh + Ah*Bl), 128x128 tile, reg-staged A (fp32) and
// B (pre-split), single-buffered 24KB LDS, XOR swizzle, reg prefetch.
// Output TAN as bf16-hi. grid (120, 2, 4): z = component.
__global__ __launch_bounds__(256) void gemm_embed_x2(
    const float* __restrict__ A0, const float* __restrict__ A1,
    const float* __restrict__ A2, const float* __restrict__ A3,
    const unsigned short* __restrict__ EW, const float* __restrict__ b_embed,
    unsigned short* __restrict__ TAN)
{
  __shared__ unsigned short sm[12288];   // Ah@0 Bh@4096 Bl@8192

  const int c = blockIdx.z;
  const float* A = (c == 0) ? A0 : (c == 1) ? A1 : (c == 2) ? A2 : A3;
  const unsigned short* Bh = EW + (size_t)c * 262144u;
  const unsigned short* Bl = Bh + 131072u;
  const float* bias = b_embed + c * 256;
  unsigned short* C = TAN + (size_t)c * 15360 * 256;

  const int t = threadIdx.x;
  const int bm = blockIdx.x * 128;
  const int bn = blockIdx.y * 128;
  const int lane = t & 63, wave = t >> 6;
  const int wm = (wave >> 1) * 64, wn = (wave & 1) * 64;
  const int fr = lane & 15, kg = lane >> 4;

  // per-thread staging: row t>>1 (0..127), khalf t&1 -> 16 elements
  const int row = t >> 1, khalf = t & 1;
  const float* aptr = A + (size_t)(bm + row) * 504 + khalf * 16;
  const unsigned short* bhp = Bh + (size_t)(bn + row) * 512 + khalf * 16;
  const unsigned short* blp = Bl + (size_t)(bn + row) * 512 + khalf * 16;
  const int axor = (row >> 1) & 3;
  const int woff0 = row * 32 + (((khalf * 2)     ^ axor) << 3);
  const int woff1 = row * 32 + (((khalf * 2 + 1) ^ axor) << 3);

  int offA[4], offB[4];
#pragma unroll
  for (int i = 0; i < 4; ++i) {
    offA[i] = frag_off(0,    wm + i * 16 + fr, kg);
    offB[i] = frag_off(4096, wn + i * 16 + fr, kg);
  }

  float4 fa0, fa1, fa2, fa3;
  int4 rb0, rb1, rl0, rl1;
  const float4 zf = make_float4(0.f, 0.f, 0.f, 0.f);
  auto loadT = [&](int k0) {
    const int gk = k0 + khalf * 16;
    fa0 = (gk      < 504) ? *reinterpret_cast<const float4*>(aptr + k0)      : zf;
    fa1 = (gk + 4  < 504) ? *reinterpret_cast<const float4*>(aptr + k0 + 4)  : zf;
    fa2 = (gk + 8  < 504) ? *reinterpret_cast<const float4*>(aptr + k0 + 8)  : zf;
    fa3 = (gk + 12 < 504) ? *reinterpret_cast<const float4*>(aptr + k0 + 12) : zf;
    rb0 = *reinterpret_cast<const int4*>(bhp + k0);
    rb1 = *reinterpret_cast<const int4*>(bhp + k0 + 8);
    rl0 = *reinterpret_cast<const int4*>(blp + k0);
    rl1 = *reinterpret_cast<const int4*>(blp + k0 + 8);
  };

  f32x4 acc[4][4] = {};
  loadT(0);

  for (int k0 = 0; k0 < 512; k0 += 32) {
    {  // stage regs -> LDS (A converted to bf16-hi)
      float xs[16] = {fa0.x, fa0.y, fa0.z, fa0.w, fa1.x, fa1.y, fa1.z, fa1.w,
                      fa2.x, fa2.y, fa2.z, fa2.w, fa3.x, fa3.y, fa3.z, fa3.w};
      bf16x8 p;
#pragma unroll
      for (int i = 0; i < 8; ++i) p[i] = (short)f2bf(xs[i]);
      *reinterpret_cast<bf16x8*>(sm + woff0) = p;
#pragma unroll
      for (int i = 0; i < 8; ++i) p[i] = (short)f2bf(xs[8 + i]);
      *reinterpret_cast<bf16x8*>(sm + woff1) = p;
      *reinterpret_cast<int4*>(sm + 4096 + woff0) = rb0;
      *reinterpret_cast<int4*>(sm + 4096 + woff1) = rb1;
      *reinterpret_cast<int4*>(sm + 8192 + woff0) = rl0;
      *reinterpret_cast<int4*>(sm + 8192 + woff1) = rl1;
    }
    __syncthreads();                     // LDS consistent
    if (k0 + 32 < 512) loadT(k0 + 32);   // reg prefetch, covered by MFMA

    bf16x8 ah[4], bh[4], bl[4];
#pragma unroll
    for (int i = 0; i < 4; ++i) {
      ah[i] = *reinterpret_cast<const bf16x8*>(sm + offA[i]);
      bh[i] = *reinterpret_cast<const bf16x8*>(sm + offB[i]);
      bl[i] = *reinterpret_cast<const bf16x8*>(sm + offB[i] + 4096);
    }
#pragma unroll
    for (int mi = 0; mi < 4; ++mi)
#pragma unroll
      for (int ni = 0; ni < 4; ++ni)
        acc[mi][ni] = __builtin_amdgcn_mfma_f32_16x16x32_bf16(ah[mi], bh[ni], acc[mi][ni], 0, 0, 0);
#pragma unroll
    for (int mi = 0; mi < 4; ++mi)
#pragma unroll
      for (int ni = 0; ni < 4; ++ni)
        acc[mi][ni] = __builtin_amdgcn_mfma_f32_16x16x32_bf16(ah[mi], bl[ni], acc[mi][ni], 0, 0, 0);
    __syncthreads();                     // reads done before next writes
  }

#pragma unroll
  for (int mi = 0; mi < 4; ++mi) {
#pragma unroll
    for (int ni = 0; ni < 4; ++ni) {
      const int col = bn + wn + ni * 16 + fr;
      const int row0 = bm + wm + mi * 16 + kg * 4;
      const float bv = bias[col];
#pragma unroll
      for (int r = 0; r < 4; ++r)
        C[(size_t)(row0 + r) * 256 + col] = f2bf(acc[mi][ni][r] + bv);
    }
  }
}

// ------------------------ LayerNorm + expmap0 -> Z (wave/row, bf16 TAN in)
__global__ __launch_bounds__(256) void ln_expmap0_k(
    const unsigned short* __restrict__ TAN, const float* __restrict__ gamma,
    const float* __restrict__ beta, float* __restrict__ Z)
{
  const int row = blockIdx.x * 4 + (threadIdx.x >> 6);   // b*30 + n
  const int lane = threadIdx.x & 63;
  const int b = row / 30;
  const int n = row % 30;

  float4 tc[4];
  float4 ts = make_float4(0.f, 0.f, 0.f, 0.f);
#pragma unroll
  for (int c = 0; c < 4; ++c) {
    ushort4 xu = *reinterpret_cast<const ushort4*>(
        TAN + ((size_t)c * 15360 + row) * 256 + lane * 4);
    float4 x = make_float4(bf2f(xu.x), bf2f(xu.y), bf2f(xu.z), bf2f(xu.w));
    float mu = wave_sum(x.x + x.y + x.z + x.w) * (1.f / 256.f);
    float4 xm = make_float4(x.x - mu, x.y - mu, x.z - mu, x.w - mu);
    float var = wave_sum(xm.x * xm.x + xm.y * xm.y + xm.z * xm.z + xm.w * xm.w)
                * (1.f / 256.f);
    float rs = rsqrtf(var + 1e-5f);
    float4 g = *reinterpret_cast<const float4*>(gamma + c * 256 + lane * 4);
    float4 be = *reinterpret_cast<const float4*>(beta + c * 256 + lane * 4);
    float4 tv = make_float4(xm.x * rs * g.x + be.x, xm.y * rs * g.y + be.y,
                            xm.z * rs * g.z + be.z, xm.w * rs * g.w + be.w);
    tc[c] = tv;
    ts.x += tv.x; ts.y += tv.y; ts.z += tv.z; ts.w += tv.w;
  }
#pragma unroll
  for (int g5 = 0; g5 < 5; ++g5) {
    float4 v = (g5 == 0) ? ts : tc[g5 - 1];
    float n2 = wave_sum(v.x * v.x + v.y * v.y + v.z * v.z + v.w * v.w);
    float nn = fmaxf(sqrtf(n2), EPS_F);
    float th = tanhf(nn);
    float w = th / nn;
    if (th > MAX_NORM_F) w *= MAX_NORM_F / fmaxf(th, EPS_F);
    float4 o = make_float4(v.x * w, v.y * w, v.z * w, v.w * w);
    *reinterpret_cast<float4*>(
        Z + (((size_t)g5 * 512 + b) * 38 + n) * 256 + lane * 4) = o;
  }
}

// ------------------------------------------------ per-pair logmap (1 wave)
__device__ __forceinline__ float4 pair_log(const float* zr, int c, int lane) {
  float4 x = *reinterpret_cast<const float4*>(zr + (size_t)c * 256 + lane * 4);
  float4 y = *reinterpret_cast<const float4*>(zr + (size_t)(c + 1) * 256 + lane * 4);
  float x2 = wave_sum(x.x * x.x + x.y * x.y + x.z * x.z + x.w * x.w);
  float y2 = wave_sum(y.x * y.x + y.y * y.y + y.z * y.z + y.w * y.w);
  float xy = wave_sum(x.x * y.x + x.y * y.y + x.z * y.z + x.w * y.w);
  float a  = 1.f - 2.f * xy + y2;
  float bb = 1.f - x2;
  float den = fmaxf(1.f - 2.f * xy + x2 * y2, EPS_F);
  float inv = 1.f / den;
  float4 u;
  u.x = (bb * y.x - a * x.x) * inv;
  u.y = (bb * y.y - a * x.y) * inv;
  u.z = (bb * y.z - a * x.z) * inv;
  u.w = (bb * y.w - a * x.w) * inv;
  float u2 = wave_sum(u.x * u.x + u.y * u.y + u.z * u.z + u.w * u.w);
  float un = fmaxf(sqrtf(u2), EPS_F);
  float coef = fmaxf(1.f - x2, EPS_F) * atanhf(fminf(un, 1.f - 1e-7f)) / un;
  float4 o;
  o.x = coef * u.x; o.y = coef * u.y; o.z = coef * u.z; o.w = coef * u.w;
  return o;
}

__device__ __forceinline__ float4 logmap0_col(const float* zr, int c, int lane) {
  float4 z = *reinterpret_cast<const float4*>(zr + (size_t)c * 256 + lane * 4);
  float z2 = wave_sum(z.x * z.x + z.y * z.y + z.z * z.z + z.w * z.w);
  float nz = fmaxf(sqrtf(z2), EPS_F);
  float cc = atanhf(fminf(nz, 1.f - 1e-7f)) / nz;
  float4 o;
  o.x = cc * z.x; o.y = cc * z.y; o.z = cc * z.z; o.w = cc * z.w;
  return o;
}

// -------------------------- velocity (t=0 full window) + feat (bf16-hi out)
__global__ __launch_bounds__(256) void vel_feat_inc_k(
    const float* __restrict__ Z, unsigned short* __restrict__ Fh,
    float* __restrict__ VSUM, int t)
{
  const int r = blockIdx.x * 4 + (threadIdx.x >> 6);
  const int lane = threadIdx.x & 63;
  const float* zr = Z + (size_t)r * 38 * 256;

  float4 vs = make_float4(0.f, 0.f, 0.f, 0.f);
#pragma unroll 1
  for (int j = 0; j < 29; ++j) {
    float4 p = pair_log(zr, t + j, lane);
    vs.x += p.x; vs.y += p.y; vs.z += p.z; vs.w += p.w;
  }
  *reinterpret_cast<float4*>(VSUM + (size_t)r * 256 + lane * 4) = vs;

  float4 fl = logmap0_col(zr, t + 29, lane);   // z_last
  float4 fp = logmap0_col(zr, t + 28, lane);   // z_prev
  const size_t fb = (size_t)r * 768 + lane * 4;
  store_hi4(Fh, fb, fl);
  store_hi4(Fh, fb + 256, fp);
  const float s29 = 1.f / 29.f;
  float4 o;
  o.x = vs.x * s29; o.y = vs.y * s29; o.z = vs.z * s29; o.w = vs.w * s29;
  store_hi4(Fh, fb + 512, o);
}

// --------- fused: z_next = expmap(z_last, sum VP + b3); then (if t<7)
// incremental velocity + FEAT for step t+1.
__global__ __launch_bounds__(256) void expmap_vel_fused_k(
    float* __restrict__ Z, const float* __restrict__ VP,
    const float* __restrict__ b3, unsigned short* __restrict__ Fh,
    float* __restrict__ VSUM, int t)
{
  const int r = blockIdx.x * 4 + (threadIdx.x >> 6);
  const int lane = threadIdx.x & 63;
  float* zr = Z + (size_t)r * 38 * 256;
  float4 x = *reinterpret_cast<const float4*>(zr + (size_t)(t + 29) * 256 + lane * 4);
  float4 v = *reinterpret_cast<const float4*>(b3 + lane * 4);
#pragma unroll
  for (int p = 0; p < 8; ++p) {
    float4 a = *reinterpret_cast<const float4*>(
        VP + (size_t)p * 655360u + (size_t)r * 256 + lane * 4);
    v.x += a.x; v.y += a.y; v.z += a.z; v.w += a.w;
  }
  float x2 = wave_sum(x.x * x.x + x.y * x.y + x.z * x.z + x.w * x.w);
  float v2 = wave_sum(v.x * v.x + v.y * v.y + v.z * v.z + v.w * v.w);
  float xv = wave_sum(x.x * v.x + x.y * v.y + x.z * v.z + x.w * v.w);

  float vn = fmaxf(sqrtf(v2), EPS_F);
  float lamx = 2.f / fmaxf(1.f - x2, EPS_F);
  float s = tanhf(0.5f * lamx * vn) / vn;
  float xy = s * xv;
  float y2 = s * s * v2;
  float a  = 1.f + 2.f * xy + y2;
  float bb = 1.f - x2;
  float den = fmaxf(1.f + 2.f * xy + x2 * y2, EPS_F);
  float inv = 1.f / den;
  float4 res;
  res.x = (a * x.x + bb * s * v.x) * inv;
  res.y = (a * x.y + bb * s * v.y) * inv;
  res.z = (a * x.z + bb * s * v.z) * inv;
  res.w = (a * x.w + bb * s * v.w) * inv;
  float r2 = wave_sum(res.x * res.x + res.y * res.y + res.z * res.z + res.w * res.w);
  float rn = sqrtf(r2);
  if (rn > MAX_NORM_F) {
    float sc = MAX_NORM_F / fmaxf(rn, EPS_F);
    res.x *= sc; res.y *= sc; res.z *= sc; res.w *= sc;
    r2 = MAX_NORM_F * MAX_NORM_F;
    rn = MAX_NORM_F;
  }
  *reinterpret_cast<float4*>(zr + (size_t)(t + 30) * 256 + lane * 4) = res;

  if (t < 7) {
    float4 pm = pair_log(zr, t, lane);
    float xyn = wave_sum(x.x * res.x + x.y * res.y + x.z * res.z + x.w * res.w);
    float an  = 1.f - 2.f * xyn + r2;
    float bbn = 1.f - x2;
    float denn = fmaxf(1.f - 2.f * xyn + x2 * r2, EPS_F);
    float invn = 1.f / denn;
    float4 u;
    u.x = (bbn * res.x - an * x.x) * invn;
    u.y = (bbn * res.y - an * x.y) * invn;
    u.z = (bbn * res.z - an * x.z) * invn;
    u.w = (bbn * res.w - an * x.w) * invn;
    float u2 = wave_sum(u.x * u.x + u.y * u.y + u.z * u.z + u.w * u.w);
    float un = fmaxf(sqrtf(u2), EPS_F);
    float coef = fmaxf(1.f - x2, EPS_F) * atanhf(fminf(un, 1.f - 1e-7f)) / un;
    float4 vs = *reinterpret_cast<const float4*>(VSUM + (size_t)r * 256 + lane * 4);
    vs.x += coef * u.x - pm.x; vs.y += coef * u.y - pm.y;
    vs.z += coef * u.z - pm.z; vs.w += coef * u.w - pm.w;
    *reinterpret_cast<float4*>(VSUM + (size_t)r * 256 + lane * 4) = vs;

    float rnp = fmaxf(rn, EPS_F);
    float cl = atanhf(fminf(rnp, 1.f - 1e-7f)) / rnp;
    float nx = fmaxf(sqrtf(x2), EPS_F);
    float cp = atanhf(fminf(nx, 1.f - 1e-7f)) / nx;
    const size_t fb = (size_t)r * 768 + lane * 4;
    float4 o;
    o.x = cl * res.x; o.y = cl * res.y; o.z = cl * res.z; o.w = cl * res.w;
    store_hi4(Fh, fb, o);
    o.x = cp * x.x; o.y = cp * x.y; o.z = cp * x.z; o.w = cp * x.w;
    store_hi4(Fh, fb + 256, o);
    const float s29 = 1.f / 29.f;
    o.x = vs.x * s29; o.y = vs.y * s29; o.z = vs.z * s29; o.w = vs.w * s29;
    store_hi4(Fh, fb + 512, o);
  }
}

// -------------------------- logmap0 over appended cols, bf16-hi out
__global__ __launch_bounds__(256) void logmap0_rows_k(
    const float* __restrict__ Z, unsigned short* __restrict__ Uh)
{
  const int q = blockIdx.x * 4 + (threadIdx.x >> 6);
  const int lane = threadIdx.x & 63;
  const int r = q >> 3;
  const int tt = q & 7;
  float4 o = logmap0_col(Z + (size_t)r * 38 * 256, 30 + tt, lane);
  store_hi4(Uh, (size_t)q * 256 + lane * 4, o);
}

// ---------------------------------------------------------------- launcher
extern "C" void kernel_launch(void* const* d_in, const int* in_sizes, int n_in,
                              void* d_out, int out_size, void* d_ws, size_t ws_size,
                              hipStream_t stream)
{
  const float* c0 = (const float*)d_in[0];
  const float* c1 = (const float*)d_in[1];
  const float* c2 = (const float*)d_in[2];
  const float* c3 = (const float*)d_in[3];
  const float* W_embed = (const float*)d_in[4];
  const float* b_embed = (const float*)d_in[5];
  const float* ln_g    = (const float*)d_in[6];
  const float* ln_b    = (const float*)d_in[7];
  const float* W1 = (const float*)d_in[8];
  const float* b1 = (const float*)d_in[9];
  const float* W2 = (const float*)d_in[10];
  const float* b2 = (const float*)d_in[11];
  const float* W3 = (const float*)d_in[12];
  const float* b3 = (const float*)d_in[13];
  const float* W_out = (const float*)d_in[14];
  const float* b_out = (const float*)d_in[15];
  float* out = (float*)d_out;
  float* ws  = (float*)d_ws;

  // ---- ws layout (floats). Peak = Z(24,903,680) + R region = within 162.5MB.
  float* Z = ws;
  unsigned short* Rs = (unsigned short*)(ws + 24903680u);
  unsigned short* TAN = Rs + 20000000u;             // 4*15360*256 shorts (stage A)
  unsigned short* W1h = Rs;                         // [1024][768]
  unsigned short* W1l = Rs + 786432u;
  unsigned short* W2h = Rs + 1572864u;              // [1024][1024]
  unsigned short* W2l = Rs + 2621440u;
  unsigned short* W3h = Rs + 3670016u;              // [256][1024]
  unsigned short* W3l = Rs + 3932160u;
  unsigned short* Woh = Rs + 4194304u;              // [504][256]
  unsigned short* Wol = Rs + 4323328u;
  unsigned short* FEATh = Rs + 4452352u;            // [2560][768]
  unsigned short* H1h = Rs + 6418432u;              // [2560][1024]
  unsigned short* H2h = Rs + 9039872u;              // [2560][1024]
  unsigned short* Uh  = Rs + 11661312u;             // [20480][256] (stage C)
  float* VP   = ws + 34338816u;                     // 8 x 2560*256 parts
  float* VSUM = ws + 39581696u;                     // 2560*256

  // ---- d_out scratch: embed weights (stage A only; final GEMM overwrites).
  unsigned short* EW = (unsigned short*)d_out;      // 4 x (h 131072 | l 131072)

  dim3 blk(256);

  // Stage A: embed weight split -> embed GEMM (x2, TAN bf16) -> LN+expmap0
  {
    WS4 d;
    for (int c = 0; c < 4; ++c) {
      d.W[c] = W_embed + (size_t)c * 504 * 256;
      d.Th[c] = EW + (size_t)c * 262144u;
      d.Tl[c] = EW + (size_t)c * 262144u + 131072u;
      d.K[c] = 504; d.N[c] = 256; d.Kp[c] = 512;
    }
    wsplit_all_k<<<dim3(4, 8, 4), blk, 0, stream>>>(d);
  }
  gemm_embed_x2<<<dim3(120, 2, 4), blk, 0, stream>>>(
      c0, c1, c2, c3, EW, b_embed, TAN);
  ln_expmap0_k<<<dim3(3840), blk, 0, stream>>>(TAN, ln_g, ln_b, Z);

  // MLP/out weight splits in one launch (TAN dead now? no — TAN is high in
  // region, weights low: disjoint; order irrelevant)
  {
    WS4 d;
    d.W[0] = W1;    d.Th[0] = W1h; d.Tl[0] = W1l; d.K[0] = 768;  d.N[0] = 1024; d.Kp[0] = 768;
    d.W[1] = W2;    d.Th[1] = W2h; d.Tl[1] = W2l; d.K[1] = 1024; d.N[1] = 1024; d.Kp[1] = 1024;
    d.W[2] = W3;    d.Th[2] = W3h; d.Tl[2] = W3l; d.K[2] = 1024; d.N[2] = 256;  d.Kp[2] = 1024;
    d.W[3] = W_out; d.Th[3] = Woh; d.Tl[3] = Wol; d.K[3] = 256;  d.N[3] = 504;  d.Kp[3] = 256;
    wsplit_all_k<<<dim3(16, 16, 4), blk, 0, stream>>>(d);
  }

  // Stage B: 8 recurrent steps (velocity/feat fused into expmap)
  vel_feat_inc_k<<<dim3(640), blk, 0, stream>>>(Z, FEATh, VSUM, 0);
  for (int t = 0; t < 8; ++t) {
    gemm_n64_x2<<<dim3(20, 16, 1), blk, 0, stream>>>(
        FEATh, 768, W1h, W1l, 768, b1, nullptr, H1h,
        1024, 2560, 1024, 768, 768, 1);
    gemm_n64_x2<<<dim3(20, 16, 1), blk, 0, stream>>>(
        H1h, 1024, W2h, W2l, 1024, b2, nullptr, H2h,
        1024, 2560, 1024, 1024, 1024, 1);
    gemm_n64_x2<<<dim3(20, 4, 8), blk, 0, stream>>>(
        H2h, 1024, W3h, W3l, 1024, nullptr, VP, nullptr,
        256, 2560, 256, 1024, 128, 0);
    expmap_vel_fused_k<<<dim3(640), blk, 0, stream>>>(
        Z, VP, b3, FEATh, VSUM, t);
  }

  // Stage C: logmap0 -> final projection into d_out
  logmap0_rows_k<<<dim3(5120), blk, 0, stream>>>(Z, Uh);
  gemm_n64_x2<<<dim3(160, 8, 1), blk, 0, stream>>>(
      Uh, 256, Woh, Wol, 256, b_out, out, nullptr,
      504, 20480, 504, 256, 256, 0);
}

// Round 9
// 660.444 us; speedup vs baseline: 1.4268x; 1.0882x over previous
//
#include <hip/hip_runtime.h>
#include <cstddef>
#include <cstdint>

#define EPS_F 1e-7f
#define MAX_NORM_F 0.99999f   // (1 - 1e-5) / SC, SC = 1

typedef __attribute__((ext_vector_type(8))) short bf16x8;  // 8 bf16 (4 VGPR)
typedef __attribute__((ext_vector_type(4))) float f32x4;

// ---------------------------------------------------------------- helpers
__device__ __forceinline__ unsigned short f2bf(float x) {
  unsigned int u = __float_as_uint(x);
  unsigned int r = u + 0x7FFFu + ((u >> 16) & 1u);   // RNE (no NaN in data)
  return (unsigned short)(r >> 16);
}
__device__ __forceinline__ float bf2f(unsigned short h) {
  return __uint_as_float(((unsigned int)h) << 16);
}

__device__ __forceinline__ float wave_sum(float v) {
#pragma unroll
  for (int off = 32; off; off >>= 1) v += __shfl_xor(v, off);
  return v;
}

__device__ __forceinline__ void store_hi4(unsigned short* H, size_t idx, float4 v) {
  ushort4 h;
  h.x = f2bf(v.x); h.y = f2bf(v.y); h.z = f2bf(v.z); h.w = f2bf(v.w);
  *reinterpret_cast<ushort4*>(H + idx) = h;
}

// async global->LDS, 16B per lane; LDS dest = uniform base + lane*16
__device__ __forceinline__ void gl_lds16(const unsigned short* g, unsigned short* l) {
  __builtin_amdgcn_global_load_lds(
      (const __attribute__((address_space(1))) void*)g,
      (__attribute__((address_space(3))) void*)l, 16, 0, 0);
}

// fragment read offset (elements) for logical row r, k-group kg, tile base tb
__device__ __forceinline__ int frag_off(int tb, int r, int kg) {
  return tb + r * 32 + ((kg ^ ((r >> 1) & 3)) << 3);
}

// ------------------------------- A fp32 -> bf16 pre-pass (stacked, padded)
// Abf[row][512], row = c*15360 + seg-row; k>=504 zero. One wave per row.
__global__ __launch_bounds__(256) void c2bf_k(
    const float* __restrict__ A0, const float* __restrict__ A1,
    const float* __restrict__ A2, const float* __restrict__ A3,
    unsigned short* __restrict__ Abf)
{
  const int row = blockIdx.x * 4 + (threadIdx.x >> 6);   // 0..61439
  const int lane = threadIdx.x & 63;
  const int c = row / 15360;
  const int lr = row - c * 15360;
  const float* A = (c == 0) ? A0 : (c == 1) ? A1 : (c == 2) ? A2 : A3;

  float4 f0 = make_float4(0.f, 0.f, 0.f, 0.f), f1 = f0;
  if (lane < 63) {
    const float* p = A + (size_t)lr * 504 + lane * 8;
    f0 = *reinterpret_cast<const float4*>(p);
    f1 = *reinterpret_cast<const float4*>(p + 4);
  }
  bf16x8 o;
  o[0] = (short)f2bf(f0.x); o[1] = (short)f2bf(f0.y);
  o[2] = (short)f2bf(f0.z); o[3] = (short)f2bf(f0.w);
  o[4] = (short)f2bf(f1.x); o[5] = (short)f2bf(f1.y);
  o[6] = (short)f2bf(f1.z); o[7] = (short)f2bf(f1.w);
  *reinterpret_cast<bf16x8*>(Abf + (size_t)row * 512 + lane * 8) = o;
}

// --------------------------------------------- weight transpose+split pass
struct WS4 {
  const float* W[4];
  unsigned short* Th[4];
  unsigned short* Tl[4];
  int K[4], N[4], Kp[4];
};

__global__ __launch_bounds__(256) void wsplit_all_k(WS4 d) {
  const int zi = blockIdx.z;
  const float* W = d.W[zi];
  unsigned short* Th = d.Th[zi];
  unsigned short* Tl = d.Tl[zi];
  const int K = d.K[zi], N = d.N[zi], Kp = d.Kp[zi];
  const int n0 = blockIdx.x * 64, k0 = blockIdx.y * 64;
  if (n0 >= N || k0 >= Kp) return;

  __shared__ float T[64][65];
  const int t = threadIdx.x;
  {
    const int lk = t >> 2;
    const int ln = (t & 3) * 16;
    const int gk = k0 + lk;
#pragma unroll
    for (int j = 0; j < 16; j += 4) {
      float4 v = make_float4(0.f, 0.f, 0.f, 0.f);
      const int gn = n0 + ln + j;
      if (gk < K) {
        if (gn + 3 < N) {
          v = *reinterpret_cast<const float4*>(W + (size_t)gk * N + gn);
        } else {
          const float* p = W + (size_t)gk * N;
          if (gn     < N) v.x = p[gn];
          if (gn + 1 < N) v.y = p[gn + 1];
          if (gn + 2 < N) v.z = p[gn + 2];
          if (gn + 3 < N) v.w = p[gn + 3];
        }
      }
      T[lk][ln + j + 0] = v.x; T[lk][ln + j + 1] = v.y;
      T[lk][ln + j + 2] = v.z; T[lk][ln + j + 3] = v.w;
    }
  }
  __syncthreads();
  {
    const int rn = t >> 2;
    const int rk = (t & 3) * 16;
    const int gn = n0 + rn;
    if (gn < N) {
      size_t base = (size_t)gn * Kp + k0 + rk;
#pragma unroll
      for (int j = 0; j < 16; ++j) {
        float x = T[rk + j][rn];
        unsigned short h = f2bf(x);
        unsigned short l = f2bf(x - bf2f(h));
        Th[base + j] = h;
        Tl[base + j] = l;
      }
    }
  }
}

// --------------------------------------------------- MLP GEMM: x2, 128x64
// acc += Ah*Bh + Ah*Bl (A = bf16-hi activations; B = split weights).
// gl_lds staging, double-buffered 32KB LDS, 1 barrier/iter, prefetch-early.
// Output: fp32 C (split-K via blockIdx.z) if Cf, else bf16-hi Ch.
__global__ __launch_bounds__(256) void gemm_n64_x2(
    const unsigned short* __restrict__ Ah, int lda,
    const unsigned short* __restrict__ Bh, const unsigned short* __restrict__ Bl,
    int ldb,
    const float* __restrict__ bias, float* __restrict__ Cf,
    unsigned short* __restrict__ Ch,
    int ldc, int M, int N, int Ktot, int kslice, int relu)
{
  __shared__ unsigned short sm[16384];   // 2 x (Ah@0 Bh@4096 Bl@6144)

  const int t = threadIdx.x;
  const int bm = blockIdx.x * 128;
  const int bn = blockIdx.y * 64;
  const int z  = blockIdx.z;
  const int koff = z * kslice;
  const int klen = min(kslice, Ktot - koff);

  const int lane = t & 63, wave = t >> 6;
  const int wm = (wave >> 1) * 64, wn = (wave & 1) * 32;
  const int fr = lane & 15, kg = lane >> 4;

  // 16 wave-issues: j<8 Ah(i=j), j<12 Bh(i=j-8), j<16 Bl(i=j-12)
  const unsigned short* sp[4];
  int dpo[4];
#pragma unroll
  for (int q = 0; q < 4; ++q) {
    const int j = wave + 4 * q;
    int tile, i;
    if (j < 8)       { tile = 0; i = j; }
    else if (j < 12) { tile = 1; i = j - 8; }
    else             { tile = 2; i = j - 12; }
    const int row = i * 16 + (lane >> 2);
    const int chunk = (lane & 3) ^ ((row >> 1) & 3);
    const unsigned short* base = (tile == 0) ? Ah : (tile == 1) ? Bh : Bl;
    const int ld = (tile == 0) ? lda : ldb;
    const int grow = (tile == 0) ? (bm + row) : min(bn + row, N - 1);
    const int tb = (tile == 0) ? 0 : (tile == 1) ? 4096 : 6144;
    sp[q] = base + (size_t)grow * ld + koff + chunk * 8;
    dpo[q] = tb + i * 512 + lane * 8;
  }

  int offA[4], offB[2];
#pragma unroll
  for (int i = 0; i < 4; ++i) offA[i] = frag_off(0, wm + i * 16 + fr, kg);
#pragma unroll
  for (int i = 0; i < 2; ++i) offB[i] = frag_off(4096, wn + i * 16 + fr, kg);

  f32x4 acc[4][2] = {};
#pragma unroll
  for (int q = 0; q < 4; ++q) gl_lds16(sp[q], sm + dpo[q]);

  int cur = 0;
  for (int k0 = 0; k0 < klen; k0 += 32) {
    __syncthreads();                     // buf[cur] staged
    if (k0 + 32 < klen) {
      unsigned short* nb = sm + (cur ^ 1) * 8192;
#pragma unroll
      for (int q = 0; q < 4; ++q) { sp[q] += 32; gl_lds16(sp[q], nb + dpo[q]); }
    }
    const unsigned short* s = sm + cur * 8192;
    bf16x8 ah[4], bh[2], bl[2];
#pragma unroll
    for (int i = 0; i < 4; ++i)
      ah[i] = *reinterpret_cast<const bf16x8*>(s + offA[i]);
#pragma unroll
    for (int i = 0; i < 2; ++i) {
      bh[i] = *reinterpret_cast<const bf16x8*>(s + offB[i]);
      bl[i] = *reinterpret_cast<const bf16x8*>(s + offB[i] + 2048);
    }
    // pass-major
#pragma unroll
    for (int mi = 0; mi < 4; ++mi)
#pragma unroll
      for (int ni = 0; ni < 2; ++ni)
        acc[mi][ni] = __builtin_amdgcn_mfma_f32_16x16x32_bf16(ah[mi], bh[ni], acc[mi][ni], 0, 0, 0);
#pragma unroll
    for (int mi = 0; mi < 4; ++mi)
#pragma unroll
      for (int ni = 0; ni < 2; ++ni)
        acc[mi][ni] = __builtin_amdgcn_mfma_f32_16x16x32_bf16(ah[mi], bl[ni], acc[mi][ni], 0, 0, 0);
    cur ^= 1;
  }

#pragma unroll
  for (int mi = 0; mi < 4; ++mi) {
#pragma unroll
    for (int ni = 0; ni < 2; ++ni) {
      const int col = bn + wn + ni * 16 + fr;
      if (col >= N) continue;
      const int row0 = bm + wm + mi * 16 + kg * 4;
      const float bv = bias ? bias[col] : 0.f;
      if (Cf) {
        float* Cz = Cf + (size_t)z * (size_t)M * (size_t)N;
#pragma unroll
        for (int r = 0; r < 4; ++r) {
          float v = acc[mi][ni][r] + bv;
          if (relu) v = fmaxf(v, 0.f);
          Cz[(size_t)(row0 + r) * ldc + col] = v;
        }
      } else {
#pragma unroll
        for (int r = 0; r < 4; ++r) {
          float v = acc[mi][ni][r] + bv;
          if (relu) v = fmaxf(v, 0.f);
          Ch[(size_t)(row0 + r) * ldc + col] = f2bf(v);
        }
      }
    }
  }
}

// ---- embed GEMM: x2 (Ah*Bh + Ah*Bl), all-bf16, all-gl_lds, 128x128 tile,
// dbuf 48KB LDS, 1 barrier/iter. A = Abf[61440][512]; TAN bf16-hi out.
// grid (480, 2): comp c = bx/120 (tiles never straddle: 15360/128 = 120).
__global__ __launch_bounds__(256) void gemm_embed2(
    const unsigned short* __restrict__ Abf, const unsigned short* __restrict__ EW,
    const float* __restrict__ b_embed, unsigned short* __restrict__ TAN)
{
  __shared__ unsigned short sm[24576];   // 2 x (Ah@0 Bh@4096 Bl@8192)

  const int t = threadIdx.x;
  const int bx = blockIdx.x;
  const int bm = bx * 128;               // global row into Abf/TAN
  const int bn = blockIdx.y * 128;       // 0 or 128
  const int c  = bx / 120;
  const unsigned short* Bh = EW + (size_t)c * 262144u;
  const unsigned short* Bl = Bh + 131072u;
  const float* bias = b_embed + c * 256;

  const int lane = t & 63, wave = t >> 6;
  const int wm = (wave >> 1) * 64, wn = (wave & 1) * 64;
  const int fr = lane & 15, kg = lane >> 4;

  // 24 wave-issues: tile = j>>3 (0 A, 1 Bh, 2 Bl), i = j&7; j = wave + 4q
  const unsigned short* sp[6];
  int dpo[6];
#pragma unroll
  for (int q = 0; q < 6; ++q) {
    const int j = wave + 4 * q;
    const int tile = j >> 3;
    const int i = j & 7;
    const int row = i * 16 + (lane >> 2);
    const int chunk = (lane & 3) ^ ((row >> 1) & 3);
    const unsigned short* base = (tile == 0) ? Abf : (tile == 1) ? Bh : Bl;
    const int grow = (tile == 0) ? (bm + row) : (bn + row);
    const int tb = tile * 4096;
    sp[q] = base + (size_t)grow * 512 + chunk * 8;
    dpo[q] = tb + i * 512 + lane * 8;
  }

  int offA[4], offB[4];
#pragma unroll
  for (int i = 0; i < 4; ++i) {
    offA[i] = frag_off(0,    wm + i * 16 + fr, kg);
    offB[i] = frag_off(4096, wn + i * 16 + fr, kg);
  }

  f32x4 acc[4][4] = {};
#pragma unroll
  for (int q = 0; q < 6; ++q) gl_lds16(sp[q], sm + dpo[q]);

  int cur = 0;
  for (int k0 = 0; k0 < 512; k0 += 32) {
    __syncthreads();                     // buf[cur] staged (vmcnt drained)
    if (k0 + 32 < 512) {
      unsigned short* nb = sm + (cur ^ 1) * 12288;
#pragma unroll
      for (int q = 0; q < 6; ++q) { sp[q] += 32; gl_lds16(sp[q], nb + dpo[q]); }
    }
    const unsigned short* s = sm + cur * 12288;
    bf16x8 ah[4], bh[4], bl[4];
#pragma unroll
    for (int i = 0; i < 4; ++i) {
      ah[i] = *reinterpret_cast<const bf16x8*>(s + offA[i]);
      bh[i] = *reinterpret_cast<const bf16x8*>(s + offB[i]);
      bl[i] = *reinterpret_cast<const bf16x8*>(s + offB[i] + 4096);
    }
    // pass-major: 16 independent MFMAs per pass
#pragma unroll
    for (int mi = 0; mi < 4; ++mi)
#pragma unroll
      for (int ni = 0; ni < 4; ++ni)
        acc[mi][ni] = __builtin_amdgcn_mfma_f32_16x16x32_bf16(ah[mi], bh[ni], acc[mi][ni], 0, 0, 0);
#pragma unroll
    for (int mi = 0; mi < 4; ++mi)
#pragma unroll
      for (int ni = 0; ni < 4; ++ni)
        acc[mi][ni] = __builtin_amdgcn_mfma_f32_16x16x32_bf16(ah[mi], bl[ni], acc[mi][ni], 0, 0, 0);
    cur ^= 1;
  }

#pragma unroll
  for (int mi = 0; mi < 4; ++mi) {
#pragma unroll
    for (int ni = 0; ni < 4; ++ni) {
      const int col = bn + wn + ni * 16 + fr;
      const int row0 = bm + wm + mi * 16 + kg * 4;
      const float bv = bias[col];
#pragma unroll
      for (int r = 0; r < 4; ++r)
        TAN[(size_t)(row0 + r) * 256 + col] = f2bf(acc[mi][ni][r] + bv);
    }
  }
}

// ------------------------ LayerNorm + expmap0 -> Z (wave/row, bf16 TAN in)
__global__ __launch_bounds__(256) void ln_expmap0_k(
    const unsigned short* __restrict__ TAN, const float* __restrict__ gamma,
    const float* __restrict__ beta, float* __restrict__ Z)
{
  const int row = blockIdx.x * 4 + (threadIdx.x >> 6);   // b*30 + n
  const int lane = threadIdx.x & 63;
  const int b = row / 30;
  const int n = row % 30;

  float4 tc[4];
  float4 ts = make_float4(0.f, 0.f, 0.f, 0.f);
#pragma unroll
  for (int c = 0; c < 4; ++c) {
    ushort4 xu = *reinterpret_cast<const ushort4*>(
        TAN + ((size_t)c * 15360 + row) * 256 + lane * 4);
    float4 x = make_float4(bf2f(xu.x), bf2f(xu.y), bf2f(xu.z), bf2f(xu.w));
    float mu = wave_sum(x.x + x.y + x.z + x.w) * (1.f / 256.f);
    float4 xm = make_float4(x.x - mu, x.y - mu, x.z - mu, x.w - mu);
    float var = wave_sum(xm.x * xm.x + xm.y * xm.y + xm.z * xm.z + xm.w * xm.w)
                * (1.f / 256.f);
    float rs = rsqrtf(var + 1e-5f);
    float4 g = *reinterpret_cast<const float4*>(gamma + c * 256 + lane * 4);
    float4 be = *reinterpret_cast<const float4*>(beta + c * 256 + lane * 4);
    float4 tv = make_float4(xm.x * rs * g.x + be.x, xm.y * rs * g.y + be.y,
                            xm.z * rs * g.z + be.z, xm.w * rs * g.w + be.w);
    tc[c] = tv;
    ts.x += tv.x; ts.y += tv.y; ts.z += tv.z; ts.w += tv.w;
  }
#pragma unroll
  for (int g5 = 0; g5 < 5; ++g5) {
    float4 v = (g5 == 0) ? ts : tc[g5 - 1];
    float n2 = wave_sum(v.x * v.x + v.y * v.y + v.z * v.z + v.w * v.w);
    float nn = fmaxf(sqrtf(n2), EPS_F);
    float th = tanhf(nn);
    float w = th / nn;
    if (th > MAX_NORM_F) w *= MAX_NORM_F / fmaxf(th, EPS_F);
    float4 o = make_float4(v.x * w, v.y * w, v.z * w, v.w * w);
    *reinterpret_cast<float4*>(
        Z + (((size_t)g5 * 512 + b) * 38 + n) * 256 + lane * 4) = o;
  }
}

// ------------------------------------------------ per-pair logmap (1 wave)
__device__ __forceinline__ float4 pair_log(const float* zr, int c, int lane) {
  float4 x = *reinterpret_cast<const float4*>(zr + (size_t)c * 256 + lane * 4);
  float4 y = *reinterpret_cast<const float4*>(zr + (size_t)(c + 1) * 256 + lane * 4);
  float x2 = wave_sum(x.x * x.x + x.y * x.y + x.z * x.z + x.w * x.w);
  float y2 = wave_sum(y.x * y.x + y.y * y.y + y.z * y.z + y.w * y.w);
  float xy = wave_sum(x.x * y.x + x.y * y.y + x.z * y.z + x.w * y.w);
  float a  = 1.f - 2.f * xy + y2;
  float bb = 1.f - x2;
  float den = fmaxf(1.f - 2.f * xy + x2 * y2, EPS_F);
  float inv = 1.f / den;
  float4 u;
  u.x = (bb * y.x - a * x.x) * inv;
  u.y = (bb * y.y - a * x.y) * inv;
  u.z = (bb * y.z - a * x.z) * inv;
  u.w = (bb * y.w - a * x.w) * inv;
  float u2 = wave_sum(u.x * u.x + u.y * u.y + u.z * u.z + u.w * u.w);
  float un = fmaxf(sqrtf(u2), EPS_F);
  float coef = fmaxf(1.f - x2, EPS_F) * atanhf(fminf(un, 1.f - 1e-7f)) / un;
  float4 o;
  o.x = coef * u.x; o.y = coef * u.y; o.z = coef * u.z; o.w = coef * u.w;
  return o;
}

__device__ __forceinline__ float4 logmap0_col(const float* zr, int c, int lane) {
  float4 z = *reinterpret_cast<const float4*>(zr + (size_t)c * 256 + lane * 4);
  float z2 = wave_sum(z.x * z.x + z.y * z.y + z.z * z.z + z.w * z.w);
  float nz = fmaxf(sqrtf(z2), EPS_F);
  float cc = atanhf(fminf(nz, 1.f - 1e-7f)) / nz;
  float4 o;
  o.x = cc * z.x; o.y = cc * z.y; o.z = cc * z.z; o.w = cc * z.w;
  return o;
}

// -------------------------- velocity (t=0 full window) + feat (bf16-hi out)
__global__ __launch_bounds__(256) void vel_feat_inc_k(
    const float* __restrict__ Z, unsigned short* __restrict__ Fh,
    float* __restrict__ VSUM, int t)
{
  const int r = blockIdx.x * 4 + (threadIdx.x >> 6);
  const int lane = threadIdx.x & 63;
  const float* zr = Z + (size_t)r * 38 * 256;

  float4 vs = make_float4(0.f, 0.f, 0.f, 0.f);
#pragma unroll 1
  for (int j = 0; j < 29; ++j) {
    float4 p = pair_log(zr, t + j, lane);
    vs.x += p.x; vs.y += p.y; vs.z += p.z; vs.w += p.w;
  }
  *reinterpret_cast<float4*>(VSUM + (size_t)r * 256 + lane * 4) = vs;

  float4 fl = logmap0_col(zr, t + 29, lane);   // z_last
  float4 fp = logmap0_col(zr, t + 28, lane);   // z_prev
  const size_t fb = (size_t)r * 768 + lane * 4;
  store_hi4(Fh, fb, fl);
  store_hi4(Fh, fb + 256, fp);
  const float s29 = 1.f / 29.f;
  float4 o;
  o.x = vs.x * s29; o.y = vs.y * s29; o.z = vs.z * s29; o.w = vs.w * s29;
  store_hi4(Fh, fb + 512, o);
}

// --------- fused: z_next = expmap(z_last, sum VP + b3); then (if t<7)
// incremental velocity + FEAT for step t+1.
__global__ __launch_bounds__(256) void expmap_vel_fused_k(
    float* __restrict__ Z, const float* __restrict__ VP,
    const float* __restrict__ b3, unsigned short* __restrict__ Fh,
    float* __restrict__ VSUM, int t)
{
  const int r = blockIdx.x * 4 + (threadIdx.x >> 6);
  const int lane = threadIdx.x & 63;
  float* zr = Z + (size_t)r * 38 * 256;
  float4 x = *reinterpret_cast<const float4*>(zr + (size_t)(t + 29) * 256 + lane * 4);
  float4 v = *reinterpret_cast<const float4*>(b3 + lane * 4);
#pragma unroll
  for (int p = 0; p < 8; ++p) {
    float4 a = *reinterpret_cast<const float4*>(
        VP + (size_t)p * 655360u + (size_t)r * 256 + lane * 4);
    v.x += a.x; v.y += a.y; v.z += a.z; v.w += a.w;
  }
  float x2 = wave_sum(x.x * x.x + x.y * x.y + x.z * x.z + x.w * x.w);
  float v2 = wave_sum(v.x * v.x + v.y * v.y + v.z * v.z + v.w * v.w);
  float xv = wave_sum(x.x * v.x + x.y * v.y + x.z * v.z + x.w * v.w);

  float vn = fmaxf(sqrtf(v2), EPS_F);
  float lamx = 2.f / fmaxf(1.f - x2, EPS_F);
  float s = tanhf(0.5f * lamx * vn) / vn;
  float xy = s * xv;
  float y2 = s * s * v2;
  float a  = 1.f + 2.f * xy + y2;
  float bb = 1.f - x2;
  float den = fmaxf(1.f + 2.f * xy + x2 * y2, EPS_F);
  float inv = 1.f / den;
  float4 res;
  res.x = (a * x.x + bb * s * v.x) * inv;
  res.y = (a * x.y + bb * s * v.y) * inv;
  res.z = (a * x.z + bb * s * v.z) * inv;
  res.w = (a * x.w + bb * s * v.w) * inv;
  float r2 = wave_sum(res.x * res.x + res.y * res.y + res.z * res.z + res.w * res.w);
  float rn = sqrtf(r2);
  if (rn > MAX_NORM_F) {
    float sc = MAX_NORM_F / fmaxf(rn, EPS_F);
    res.x *= sc; res.y *= sc; res.z *= sc; res.w *= sc;
    r2 = MAX_NORM_F * MAX_NORM_F;
    rn = MAX_NORM_F;
  }
  *reinterpret_cast<float4*>(zr + (size_t)(t + 30) * 256 + lane * 4) = res;

  if (t < 7) {
    float4 pm = pair_log(zr, t, lane);
    float xyn = wave_sum(x.x * res.x + x.y * res.y + x.z * res.z + x.w * res.w);
    float an  = 1.f - 2.f * xyn + r2;
    float bbn = 1.f - x2;
    float denn = fmaxf(1.f - 2.f * xyn + x2 * r2, EPS_F);
    float invn = 1.f / denn;
    float4 u;
    u.x = (bbn * res.x - an * x.x) * invn;
    u.y = (bbn * res.y - an * x.y) * invn;
    u.z = (bbn * res.z - an * x.z) * invn;
    u.w = (bbn * res.w - an * x.w) * invn;
    float u2 = wave_sum(u.x * u.x + u.y * u.y + u.z * u.z + u.w * u.w);
    float un = fmaxf(sqrtf(u2), EPS_F);
    float coef = fmaxf(1.f - x2, EPS_F) * atanhf(fminf(un, 1.f - 1e-7f)) / un;
    float4 vs = *reinterpret_cast<const float4*>(VSUM + (size_t)r * 256 + lane * 4);
    vs.x += coef * u.x - pm.x; vs.y += coef * u.y - pm.y;
    vs.z += coef * u.z - pm.z; vs.w += coef * u.w - pm.w;
    *reinterpret_cast<float4*>(VSUM + (size_t)r * 256 + lane * 4) = vs;

    float rnp = fmaxf(rn, EPS_F);
    float cl = atanhf(fminf(rnp, 1.f - 1e-7f)) / rnp;
    float nx = fmaxf(sqrtf(x2), EPS_F);
    float cp = atanhf(fminf(nx, 1.f - 1e-7f)) / nx;
    const size_t fb = (size_t)r * 768 + lane * 4;
    float4 o;
    o.x = cl * res.x; o.y = cl * res.y; o.z = cl * res.z; o.w = cl * res.w;
    store_hi4(Fh, fb, o);
    o.x = cp * x.x; o.y = cp * x.y; o.z = cp * x.z; o.w = cp * x.w;
    store_hi4(Fh, fb + 256, o);
    const float s29 = 1.f / 29.f;
    o.x = vs.x * s29; o.y = vs.y * s29; o.z = vs.z * s29; o.w = vs.w * s29;
    store_hi4(Fh, fb + 512, o);
  }
}

// -------------------------- logmap0 over appended cols, bf16-hi out
__global__ __launch_bounds__(256) void logmap0_rows_k(
    const float* __restrict__ Z, unsigned short* __restrict__ Uh)
{
  const int q = blockIdx.x * 4 + (threadIdx.x >> 6);
  const int lane = threadIdx.x & 63;
  const int r = q >> 3;
  const int tt = q & 7;
  float4 o = logmap0_col(Z + (size_t)r * 38 * 256, 30 + tt, lane);
  store_hi4(Uh, (size_t)q * 256 + lane * 4, o);
}

// ---------------------------------------------------------------- launcher
extern "C" void kernel_launch(void* const* d_in, const int* in_sizes, int n_in,
                              void* d_out, int out_size, void* d_ws, size_t ws_size,
                              hipStream_t stream)
{
  const float* c0 = (const float*)d_in[0];
  const float* c1 = (const float*)d_in[1];
  const float* c2 = (const float*)d_in[2];
  const float* c3 = (const float*)d_in[3];
  const float* W_embed = (const float*)d_in[4];
  const float* b_embed = (const float*)d_in[5];
  const float* ln_g    = (const float*)d_in[6];
  const float* ln_b    = (const float*)d_in[7];
  const float* W1 = (const float*)d_in[8];
  const float* b1 = (const float*)d_in[9];
  const float* W2 = (const float*)d_in[10];
  const float* b2 = (const float*)d_in[11];
  const float* W3 = (const float*)d_in[12];
  const float* b3 = (const float*)d_in[13];
  const float* W_out = (const float*)d_in[14];
  const float* b_out = (const float*)d_in[15];
  float* out = (float*)d_out;
  float* ws  = (float*)d_ws;

  // ---- ws layout. Peak identical to R8 (proven): Z + Rs region.
  float* Z = ws;
  // Abf aliases the Z region (Z written only after embed completes):
  unsigned short* Abf = (unsigned short*)ws;        // [61440][512] bf16
  unsigned short* Rs = (unsigned short*)(ws + 24903680u);
  unsigned short* TAN = Rs + 20000000u;             // 4*15360*256 shorts
  unsigned short* W1h = Rs;                         // [1024][768]
  unsigned short* W1l = Rs + 786432u;
  unsigned short* W2h = Rs + 1572864u;              // [1024][1024]
  unsigned short* W2l = Rs + 2621440u;
  unsigned short* W3h = Rs + 3670016u;              // [256][1024]
  unsigned short* W3l = Rs + 3932160u;
  unsigned short* Woh = Rs + 4194304u;              // [504][256]
  unsigned short* Wol = Rs + 4323328u;
  unsigned short* FEATh = Rs + 4452352u;            // [2560][768]
  unsigned short* H1h = Rs + 6418432u;              // [2560][1024]
  unsigned short* H2h = Rs + 9039872u;              // [2560][1024]
  unsigned short* Uh  = Rs + 11661312u;             // [20480][256] (stage C)
  float* VP   = ws + 34338816u;                     // 8 x 2560*256 parts
  float* VSUM = ws + 39581696u;                     // 2560*256

  // ---- d_out scratch: embed weights (stage A only; final GEMM overwrites).
  unsigned short* EW = (unsigned short*)d_out;      // 4 x (h 131072 | l 131072)

  dim3 blk(256);

  // Stage A: A->bf16 pre-pass + embed weight split -> embed GEMM -> LN
  c2bf_k<<<dim3(15360), blk, 0, stream>>>(c0, c1, c2, c3, Abf);
  {
    WS4 d;
    for (int c = 0; c < 4; ++c) {
      d.W[c] = W_embed + (size_t)c * 504 * 256;
      d.Th[c] = EW + (size_t)c * 262144u;
      d.Tl[c] = EW + (size_t)c * 262144u + 131072u;
      d.K[c] = 504; d.N[c] = 256; d.Kp[c] = 512;
    }
    wsplit_all_k<<<dim3(4, 8, 4), blk, 0, stream>>>(d);
  }
  gemm_embed2<<<dim3(480, 2), blk, 0, stream>>>(Abf, EW, b_embed, TAN);
  ln_expmap0_k<<<dim3(3840), blk, 0, stream>>>(TAN, ln_g, ln_b, Z);

  // MLP/out weight splits in one launch
  {
    WS4 d;
    d.W[0] = W1;    d.Th[0] = W1h; d.Tl[0] = W1l; d.K[0] = 768;  d.N[0] = 1024; d.Kp[0] = 768;
    d.W[1] = W2;    d.Th[1] = W2h; d.Tl[1] = W2l; d.K[1] = 1024; d.N[1] = 1024; d.Kp[1] = 1024;
    d.W[2] = W3;    d.Th[2] = W3h; d.Tl[2] = W3l; d.K[2] = 1024; d.N[2] = 256;  d.Kp[2] = 1024;
    d.W[3] = W_out; d.Th[3] = Woh; d.Tl[3] = Wol; d.K[3] = 256;  d.N[3] = 504;  d.Kp[3] = 256;
    wsplit_all_k<<<dim3(16, 16, 4), blk, 0, stream>>>(d);
  }

  // Stage B: 8 recurrent steps (velocity/feat fused into expmap)
  vel_feat_inc_k<<<dim3(640), blk, 0, stream>>>(Z, FEATh, VSUM, 0);
  for (int t = 0; t < 8; ++t) {
    gemm_n64_x2<<<dim3(20, 16, 1), blk, 0, stream>>>(
        FEATh, 768, W1h, W1l, 768, b1, nullptr, H1h,
        1024, 2560, 1024, 768, 768, 1);
    gemm_n64_x2<<<dim3(20, 16, 1), blk, 0, stream>>>(
        H1h, 1024, W2h, W2l, 1024, b2, nullptr, H2h,
        1024, 2560, 1024, 1024, 1024, 1);
    gemm_n64_x2<<<dim3(20, 4, 8), blk, 0, stream>>>(
        H2h, 1024, W3h, W3l, 1024, nullptr, VP, nullptr,
        256, 2560, 256, 1024, 128, 0);
    expmap_vel_fused_k<<<dim3(640), blk, 0, stream>>>(
        Z, VP, b3, FEATh, VSUM, t);
  }

  // Stage C: logmap0 -> final projection into d_out
  logmap0_rows_k<<<dim3(5120), blk, 0, stream>>>(Z, Uh);
  gemm_n64_x2<<<dim3(160, 8, 1), blk, 0, stream>>>(
      Uh, 256, Woh, Wol, 256, b_out, out, nullptr,
      504, 20480, 504, 256, 256, 0);
}

// Round 10
// 593.225 us; speedup vs baseline: 1.5885x; 1.1133x over previous
//
#include <hip/hip_runtime.h>
#include <cstddef>
#include <cstdint>

#define EPS_F 1e-7f
#define MAX_NORM_F 0.99999f   // (1 - 1e-5) / SC, SC = 1

typedef __attribute__((ext_vector_type(8))) short bf16x8;  // 8 bf16 (4 VGPR)
typedef __attribute__((ext_vector_type(4))) float f32x4;

// ---------------------------------------------------------------- helpers
__device__ __forceinline__ unsigned short f2bf(float x) {
  unsigned int u = __float_as_uint(x);
  unsigned int r = u + 0x7FFFu + ((u >> 16) & 1u);   // RNE (no NaN in data)
  return (unsigned short)(r >> 16);
}
__device__ __forceinline__ float bf2f(unsigned short h) {
  return __uint_as_float(((unsigned int)h) << 16);
}

__device__ __forceinline__ float wave_sum(float v) {
#pragma unroll
  for (int off = 32; off; off >>= 1) v += __shfl_xor(v, off);
  return v;
}

__device__ __forceinline__ void store_hi4(unsigned short* H, size_t idx, float4 v) {
  ushort4 h;
  h.x = f2bf(v.x); h.y = f2bf(v.y); h.z = f2bf(v.z); h.w = f2bf(v.w);
  *reinterpret_cast<ushort4*>(H + idx) = h;
}

// async global->LDS, 16B per lane; LDS dest = uniform base + lane*16
__device__ __forceinline__ void gl_lds16(const unsigned short* g, unsigned short* l) {
  __builtin_amdgcn_global_load_lds(
      (const __attribute__((address_space(1))) void*)g,
      (__attribute__((address_space(3))) void*)l, 16, 0, 0);
}

// fragment read offset (elements) for logical row r, k-group kg, tile base tb
__device__ __forceinline__ int frag_off(int tb, int r, int kg) {
  return tb + r * 32 + ((kg ^ ((r >> 1) & 3)) << 3);
}

// ------------------------------- A fp32 -> bf16 pre-pass (stacked, padded)
__global__ __launch_bounds__(256) void c2bf_k(
    const float* __restrict__ A0, const float* __restrict__ A1,
    const float* __restrict__ A2, const float* __restrict__ A3,
    unsigned short* __restrict__ Abf)
{
  const int row = blockIdx.x * 4 + (threadIdx.x >> 6);   // 0..61439
  const int lane = threadIdx.x & 63;
  const int c = row / 15360;
  const int lr = row - c * 15360;
  const float* A = (c == 0) ? A0 : (c == 1) ? A1 : (c == 2) ? A2 : A3;

  float4 f0 = make_float4(0.f, 0.f, 0.f, 0.f), f1 = f0;
  if (lane < 63) {
    const float* p = A + (size_t)lr * 504 + lane * 8;
    f0 = *reinterpret_cast<const float4*>(p);
    f1 = *reinterpret_cast<const float4*>(p + 4);
  }
  bf16x8 o;
  o[0] = (short)f2bf(f0.x); o[1] = (short)f2bf(f0.y);
  o[2] = (short)f2bf(f0.z); o[3] = (short)f2bf(f0.w);
  o[4] = (short)f2bf(f1.x); o[5] = (short)f2bf(f1.y);
  o[6] = (short)f2bf(f1.z); o[7] = (short)f2bf(f1.w);
  *reinterpret_cast<bf16x8*>(Abf + (size_t)row * 512 + lane * 8) = o;
}

// --------------------------------------------- weight transpose+split pass
struct WS4 {
  const float* W[4];
  unsigned short* Th[4];
  unsigned short* Tl[4];
  int K[4], N[4], Kp[4];
};

__global__ __launch_bounds__(256) void wsplit_all_k(WS4 d) {
  const int zi = blockIdx.z;
  const float* W = d.W[zi];
  unsigned short* Th = d.Th[zi];
  unsigned short* Tl = d.Tl[zi];
  const int K = d.K[zi], N = d.N[zi], Kp = d.Kp[zi];
  const int n0 = blockIdx.x * 64, k0 = blockIdx.y * 64;
  if (n0 >= N || k0 >= Kp) return;

  __shared__ float T[64][65];
  const int t = threadIdx.x;
  {
    const int lk = t >> 2;
    const int ln = (t & 3) * 16;
    const int gk = k0 + lk;
#pragma unroll
    for (int j = 0; j < 16; j += 4) {
      float4 v = make_float4(0.f, 0.f, 0.f, 0.f);
      const int gn = n0 + ln + j;
      if (gk < K) {
        if (gn + 3 < N) {
          v = *reinterpret_cast<const float4*>(W + (size_t)gk * N + gn);
        } else {
          const float* p = W + (size_t)gk * N;
          if (gn     < N) v.x = p[gn];
          if (gn + 1 < N) v.y = p[gn + 1];
          if (gn + 2 < N) v.z = p[gn + 2];
          if (gn + 3 < N) v.w = p[gn + 3];
        }
      }
      T[lk][ln + j + 0] = v.x; T[lk][ln + j + 1] = v.y;
      T[lk][ln + j + 2] = v.z; T[lk][ln + j + 3] = v.w;
    }
  }
  __syncthreads();
  {
    const int rn = t >> 2;
    const int rk = (t & 3) * 16;
    const int gn = n0 + rn;
    if (gn < N) {
      size_t base = (size_t)gn * Kp + k0 + rk;
#pragma unroll
      for (int j = 0; j < 16; ++j) {
        float x = T[rk + j][rn];
        unsigned short h = f2bf(x);
        unsigned short l = f2bf(x - bf2f(h));
        Th[base + j] = h;
        Tl[base + j] = l;
      }
    }
  }
}

// --------------------------------------------------- MLP GEMM: x1, 128x64
// acc += Ah*Bh (bf16-hi activations AND weights). gl_lds staging,
// double-buffered 24KB LDS, 1 barrier/iter, prefetch-early.
// Output: fp32 C (split-K via blockIdx.z) if Cf, else bf16-hi Ch.
__global__ __launch_bounds__(256) void gemm_n64_x1(
    const unsigned short* __restrict__ Ah, int lda,
    const unsigned short* __restrict__ Bh, int ldb,
    const float* __restrict__ bias, float* __restrict__ Cf,
    unsigned short* __restrict__ Ch,
    int ldc, int M, int N, int Ktot, int kslice, int relu)
{
  __shared__ unsigned short sm[12288];   // 2 x (Ah@0 Bh@4096)

  const int t = threadIdx.x;
  const int bm = blockIdx.x * 128;
  const int bn = blockIdx.y * 64;
  const int z  = blockIdx.z;
  const int koff = z * kslice;
  const int klen = min(kslice, Ktot - koff);

  const int lane = t & 63, wave = t >> 6;
  const int wm = (wave >> 1) * 64, wn = (wave & 1) * 32;
  const int fr = lane & 15, kg = lane >> 4;

  // 12 wave-issues: j<8 Ah(i=j), j<12 Bh(i=j-8)
  const unsigned short* sp[3];
  int dpo[3];
#pragma unroll
  for (int q = 0; q < 3; ++q) {
    const int j = wave + 4 * q;
    int tile, i;
    if (j < 8) { tile = 0; i = j; }
    else       { tile = 1; i = j - 8; }
    const int row = i * 16 + (lane >> 2);
    const int chunk = (lane & 3) ^ ((row >> 1) & 3);
    const unsigned short* base = (tile == 0) ? Ah : Bh;
    const int ld = (tile == 0) ? lda : ldb;
    const int grow = (tile == 0) ? (bm + row) : min(bn + row, N - 1);
    const int tb = (tile == 0) ? 0 : 4096;
    sp[q] = base + (size_t)grow * ld + koff + chunk * 8;
    dpo[q] = tb + i * 512 + lane * 8;
  }

  int offA[4], offB[2];
#pragma unroll
  for (int i = 0; i < 4; ++i) offA[i] = frag_off(0, wm + i * 16 + fr, kg);
#pragma unroll
  for (int i = 0; i < 2; ++i) offB[i] = frag_off(4096, wn + i * 16 + fr, kg);

  f32x4 acc[4][2] = {};
#pragma unroll
  for (int q = 0; q < 3; ++q) gl_lds16(sp[q], sm + dpo[q]);

  int cur = 0;
  for (int k0 = 0; k0 < klen; k0 += 32) {
    __syncthreads();                     // buf[cur] staged
    if (k0 + 32 < klen) {
      unsigned short* nb = sm + (cur ^ 1) * 6144;
#pragma unroll
      for (int q = 0; q < 3; ++q) { sp[q] += 32; gl_lds16(sp[q], nb + dpo[q]); }
    }
    const unsigned short* s = sm + cur * 6144;
    bf16x8 ah[4], bh[2];
#pragma unroll
    for (int i = 0; i < 4; ++i)
      ah[i] = *reinterpret_cast<const bf16x8*>(s + offA[i]);
#pragma unroll
    for (int i = 0; i < 2; ++i)
      bh[i] = *reinterpret_cast<const bf16x8*>(s + offB[i]);
#pragma unroll
    for (int mi = 0; mi < 4; ++mi)
#pragma unroll
      for (int ni = 0; ni < 2; ++ni)
        acc[mi][ni] = __builtin_amdgcn_mfma_f32_16x16x32_bf16(ah[mi], bh[ni], acc[mi][ni], 0, 0, 0);
    cur ^= 1;
  }

#pragma unroll
  for (int mi = 0; mi < 4; ++mi) {
#pragma unroll
    for (int ni = 0; ni < 2; ++ni) {
      const int col = bn + wn + ni * 16 + fr;
      if (col >= N) continue;
      const int row0 = bm + wm + mi * 16 + kg * 4;
      const float bv = bias ? bias[col] : 0.f;
      if (Cf) {
        float* Cz = Cf + (size_t)z * (size_t)M * (size_t)N;
#pragma unroll
        for (int r = 0; r < 4; ++r) {
          float v = acc[mi][ni][r] + bv;
          if (relu) v = fmaxf(v, 0.f);
          Cz[(size_t)(row0 + r) * ldc + col] = v;
        }
      } else {
#pragma unroll
        for (int r = 0; r < 4; ++r) {
          float v = acc[mi][ni][r] + bv;
          if (relu) v = fmaxf(v, 0.f);
          Ch[(size_t)(row0 + r) * ldc + col] = f2bf(v);
        }
      }
    }
  }
}

// --------------------------------------------------- GEMM: x2, 128x64
// acc += Ah*Bh + Ah*Bl (split weights). Used for the final W_out GEMM.
__global__ __launch_bounds__(256) void gemm_n64_x2(
    const unsigned short* __restrict__ Ah, int lda,
    const unsigned short* __restrict__ Bh, const unsigned short* __restrict__ Bl,
    int ldb,
    const float* __restrict__ bias, float* __restrict__ Cf,
    unsigned short* __restrict__ Ch,
    int ldc, int M, int N, int Ktot, int kslice, int relu)
{
  __shared__ unsigned short sm[16384];   // 2 x (Ah@0 Bh@4096 Bl@6144)

  const int t = threadIdx.x;
  const int bm = blockIdx.x * 128;
  const int bn = blockIdx.y * 64;
  const int z  = blockIdx.z;
  const int koff = z * kslice;
  const int klen = min(kslice, Ktot - koff);

  const int lane = t & 63, wave = t >> 6;
  const int wm = (wave >> 1) * 64, wn = (wave & 1) * 32;
  const int fr = lane & 15, kg = lane >> 4;

  const unsigned short* sp[4];
  int dpo[4];
#pragma unroll
  for (int q = 0; q < 4; ++q) {
    const int j = wave + 4 * q;
    int tile, i;
    if (j < 8)       { tile = 0; i = j; }
    else if (j < 12) { tile = 1; i = j - 8; }
    else             { tile = 2; i = j - 12; }
    const int row = i * 16 + (lane >> 2);
    const int chunk = (lane & 3) ^ ((row >> 1) & 3);
    const unsigned short* base = (tile == 0) ? Ah : (tile == 1) ? Bh : Bl;
    const int ld = (tile == 0) ? lda : ldb;
    const int grow = (tile == 0) ? (bm + row) : min(bn + row, N - 1);
    const int tb = (tile == 0) ? 0 : (tile == 1) ? 4096 : 6144;
    sp[q] = base + (size_t)grow * ld + koff + chunk * 8;
    dpo[q] = tb + i * 512 + lane * 8;
  }

  int offA[4], offB[2];
#pragma unroll
  for (int i = 0; i < 4; ++i) offA[i] = frag_off(0, wm + i * 16 + fr, kg);
#pragma unroll
  for (int i = 0; i < 2; ++i) offB[i] = frag_off(4096, wn + i * 16 + fr, kg);

  f32x4 acc[4][2] = {};
#pragma unroll
  for (int q = 0; q < 4; ++q) gl_lds16(sp[q], sm + dpo[q]);

  int cur = 0;
  for (int k0 = 0; k0 < klen; k0 += 32) {
    __syncthreads();
    if (k0 + 32 < klen) {
      unsigned short* nb = sm + (cur ^ 1) * 8192;
#pragma unroll
      for (int q = 0; q < 4; ++q) { sp[q] += 32; gl_lds16(sp[q], nb + dpo[q]); }
    }
    const unsigned short* s = sm + cur * 8192;
    bf16x8 ah[4], bh[2], bl[2];
#pragma unroll
    for (int i = 0; i < 4; ++i)
      ah[i] = *reinterpret_cast<const bf16x8*>(s + offA[i]);
#pragma unroll
    for (int i = 0; i < 2; ++i) {
      bh[i] = *reinterpret_cast<const bf16x8*>(s + offB[i]);
      bl[i] = *reinterpret_cast<const bf16x8*>(s + offB[i] + 2048);
    }
#pragma unroll
    for (int mi = 0; mi < 4; ++mi)
#pragma unroll
      for (int ni = 0; ni < 2; ++ni)
        acc[mi][ni] = __builtin_amdgcn_mfma_f32_16x16x32_bf16(ah[mi], bh[ni], acc[mi][ni], 0, 0, 0);
#pragma unroll
    for (int mi = 0; mi < 4; ++mi)
#pragma unroll
      for (int ni = 0; ni < 2; ++ni)
        acc[mi][ni] = __builtin_amdgcn_mfma_f32_16x16x32_bf16(ah[mi], bl[ni], acc[mi][ni], 0, 0, 0);
    cur ^= 1;
  }

#pragma unroll
  for (int mi = 0; mi < 4; ++mi) {
#pragma unroll
    for (int ni = 0; ni < 2; ++ni) {
      const int col = bn + wn + ni * 16 + fr;
      if (col >= N) continue;
      const int row0 = bm + wm + mi * 16 + kg * 4;
      const float bv = bias ? bias[col] : 0.f;
      if (Cf) {
        float* Cz = Cf + (size_t)z * (size_t)M * (size_t)N;
#pragma unroll
        for (int r = 0; r < 4; ++r) {
          float v = acc[mi][ni][r] + bv;
          if (relu) v = fmaxf(v, 0.f);
          Cz[(size_t)(row0 + r) * ldc + col] = v;
        }
      } else {
#pragma unroll
        for (int r = 0; r < 4; ++r) {
          float v = acc[mi][ni][r] + bv;
          if (relu) v = fmaxf(v, 0.f);
          Ch[(size_t)(row0 + r) * ldc + col] = f2bf(v);
        }
      }
    }
  }
}

// ---- embed GEMM: x2 (Ah*Bh + Ah*Bl), all-bf16, all-gl_lds, 128x128 tile,
// dbuf 48KB LDS, 1 barrier/iter. A = Abf[61440][512]; TAN bf16-hi out.
__global__ __launch_bounds__(256) void gemm_embed2(
    const unsigned short* __restrict__ Abf, const unsigned short* __restrict__ EW,
    const float* __restrict__ b_embed, unsigned short* __restrict__ TAN)
{
  __shared__ unsigned short sm[24576];   // 2 x (Ah@0 Bh@4096 Bl@8192)

  const int t = threadIdx.x;
  const int bx = blockIdx.x;
  const int bm = bx * 128;               // global row into Abf/TAN
  const int bn = blockIdx.y * 128;       // 0 or 128
  const int c  = bx / 120;
  const unsigned short* Bh = EW + (size_t)c * 262144u;
  const unsigned short* Bl = Bh + 131072u;
  const float* bias = b_embed + c * 256;

  const int lane = t & 63, wave = t >> 6;
  const int wm = (wave >> 1) * 64, wn = (wave & 1) * 64;
  const int fr = lane & 15, kg = lane >> 4;

  const unsigned short* sp[6];
  int dpo[6];
#pragma unroll
  for (int q = 0; q < 6; ++q) {
    const int j = wave + 4 * q;
    const int tile = j >> 3;
    const int i = j & 7;
    const int row = i * 16 + (lane >> 2);
    const int chunk = (lane & 3) ^ ((row >> 1) & 3);
    const unsigned short* base = (tile == 0) ? Abf : (tile == 1) ? Bh : Bl;
    const int grow = (tile == 0) ? (bm + row) : (bn + row);
    const int tb = tile * 4096;
    sp[q] = base + (size_t)grow * 512 + chunk * 8;
    dpo[q] = tb + i * 512 + lane * 8;
  }

  int offA[4], offB[4];
#pragma unroll
  for (int i = 0; i < 4; ++i) {
    offA[i] = frag_off(0,    wm + i * 16 + fr, kg);
    offB[i] = frag_off(4096, wn + i * 16 + fr, kg);
  }

  f32x4 acc[4][4] = {};
#pragma unroll
  for (int q = 0; q < 6; ++q) gl_lds16(sp[q], sm + dpo[q]);

  int cur = 0;
  for (int k0 = 0; k0 < 512; k0 += 32) {
    __syncthreads();
    if (k0 + 32 < 512) {
      unsigned short* nb = sm + (cur ^ 1) * 12288;
#pragma unroll
      for (int q = 0; q < 6; ++q) { sp[q] += 32; gl_lds16(sp[q], nb + dpo[q]); }
    }
    const unsigned short* s = sm + cur * 12288;
    bf16x8 ah[4], bh[4], bl[4];
#pragma unroll
    for (int i = 0; i < 4; ++i) {
      ah[i] = *reinterpret_cast<const bf16x8*>(s + offA[i]);
      bh[i] = *reinterpret_cast<const bf16x8*>(s + offB[i]);
      bl[i] = *reinterpret_cast<const bf16x8*>(s + offB[i] + 4096);
    }
#pragma unroll
    for (int mi = 0; mi < 4; ++mi)
#pragma unroll
      for (int ni = 0; ni < 4; ++ni)
        acc[mi][ni] = __builtin_amdgcn_mfma_f32_16x16x32_bf16(ah[mi], bh[ni], acc[mi][ni], 0, 0, 0);
#pragma unroll
    for (int mi = 0; mi < 4; ++mi)
#pragma unroll
      for (int ni = 0; ni < 4; ++ni)
        acc[mi][ni] = __builtin_amdgcn_mfma_f32_16x16x32_bf16(ah[mi], bl[ni], acc[mi][ni], 0, 0, 0);
    cur ^= 1;
  }

#pragma unroll
  for (int mi = 0; mi < 4; ++mi) {
#pragma unroll
    for (int ni = 0; ni < 4; ++ni) {
      const int col = bn + wn + ni * 16 + fr;
      const int row0 = bm + wm + mi * 16 + kg * 4;
      const float bv = bias[col];
#pragma unroll
      for (int r = 0; r < 4; ++r)
        TAN[(size_t)(row0 + r) * 256 + col] = f2bf(acc[mi][ni][r] + bv);
    }
  }
}

// ------------------------ LayerNorm + expmap0 -> Z (wave/row, bf16 TAN in)
__global__ __launch_bounds__(256) void ln_expmap0_k(
    const unsigned short* __restrict__ TAN, const float* __restrict__ gamma,
    const float* __restrict__ beta, float* __restrict__ Z)
{
  const int row = blockIdx.x * 4 + (threadIdx.x >> 6);   // b*30 + n
  const int lane = threadIdx.x & 63;
  const int b = row / 30;
  const int n = row % 30;

  float4 tc[4];
  float4 ts = make_float4(0.f, 0.f, 0.f, 0.f);
#pragma unroll
  for (int c = 0; c < 4; ++c) {
    ushort4 xu = *reinterpret_cast<const ushort4*>(
        TAN + ((size_t)c * 15360 + row) * 256 + lane * 4);
    float4 x = make_float4(bf2f(xu.x), bf2f(xu.y), bf2f(xu.z), bf2f(xu.w));
    float mu = wave_sum(x.x + x.y + x.z + x.w) * (1.f / 256.f);
    float4 xm = make_float4(x.x - mu, x.y - mu, x.z - mu, x.w - mu);
    float var = wave_sum(xm.x * xm.x + xm.y * xm.y + xm.z * xm.z + xm.w * xm.w)
                * (1.f / 256.f);
    float rs = rsqrtf(var + 1e-5f);
    float4 g = *reinterpret_cast<const float4*>(gamma + c * 256 + lane * 4);
    float4 be = *reinterpret_cast<const float4*>(beta + c * 256 + lane * 4);
    float4 tv = make_float4(xm.x * rs * g.x + be.x, xm.y * rs * g.y + be.y,
                            xm.z * rs * g.z + be.z, xm.w * rs * g.w + be.w);
    tc[c] = tv;
    ts.x += tv.x; ts.y += tv.y; ts.z += tv.z; ts.w += tv.w;
  }
#pragma unroll
  for (int g5 = 0; g5 < 5; ++g5) {
    float4 v = (g5 == 0) ? ts : tc[g5 - 1];
    float n2 = wave_sum(v.x * v.x + v.y * v.y + v.z * v.z + v.w * v.w);
    float nn = fmaxf(sqrtf(n2), EPS_F);
    float th = tanhf(nn);
    float w = th / nn;
    if (th > MAX_NORM_F) w *= MAX_NORM_F / fmaxf(th, EPS_F);
    float4 o = make_float4(v.x * w, v.y * w, v.z * w, v.w * w);
    *reinterpret_cast<float4*>(
        Z + (((size_t)g5 * 512 + b) * 38 + n) * 256 + lane * 4) = o;
  }
}

// ------------------------------------------------ per-pair logmap (1 wave)
__device__ __forceinline__ float4 pair_log(const float* zr, int c, int lane) {
  float4 x = *reinterpret_cast<const float4*>(zr + (size_t)c * 256 + lane * 4);
  float4 y = *reinterpret_cast<const float4*>(zr + (size_t)(c + 1) * 256 + lane * 4);
  float x2 = wave_sum(x.x * x.x + x.y * x.y + x.z * x.z + x.w * x.w);
  float y2 = wave_sum(y.x * y.x + y.y * y.y + y.z * y.z + y.w * y.w);
  float xy = wave_sum(x.x * y.x + x.y * y.y + x.z * y.z + x.w * y.w);
  float a  = 1.f - 2.f * xy + y2;
  float bb = 1.f - x2;
  float den = fmaxf(1.f - 2.f * xy + x2 * y2, EPS_F);
  float inv = 1.f / den;
  float4 u;
  u.x = (bb * y.x - a * x.x) * inv;
  u.y = (bb * y.y - a * x.y) * inv;
  u.z = (bb * y.z - a * x.z) * inv;
  u.w = (bb * y.w - a * x.w) * inv;
  float u2 = wave_sum(u.x * u.x + u.y * u.y + u.z * u.z + u.w * u.w);
  float un = fmaxf(sqrtf(u2), EPS_F);
  float coef = fmaxf(1.f - x2, EPS_F) * atanhf(fminf(un, 1.f - 1e-7f)) / un;
  float4 o;
  o.x = coef * u.x; o.y = coef * u.y; o.z = coef * u.z; o.w = coef * u.w;
  return o;
}

__device__ __forceinline__ float4 logmap0_col(const float* zr, int c, int lane) {
  float4 z = *reinterpret_cast<const float4*>(zr + (size_t)c * 256 + lane * 4);
  float z2 = wave_sum(z.x * z.x + z.y * z.y + z.z * z.z + z.w * z.w);
  float nz = fmaxf(sqrtf(z2), EPS_F);
  float cc = atanhf(fminf(nz, 1.f - 1e-7f)) / nz;
  float4 o;
  o.x = cc * z.x; o.y = cc * z.y; o.z = cc * z.z; o.w = cc * z.w;
  return o;
}

// -------------------------- velocity (t=0 full window) + feat (bf16-hi out)
__global__ __launch_bounds__(256) void vel_feat_inc_k(
    const float* __restrict__ Z, unsigned short* __restrict__ Fh,
    float* __restrict__ VSUM, int t)
{
  const int r = blockIdx.x * 4 + (threadIdx.x >> 6);
  const int lane = threadIdx.x & 63;
  const float* zr = Z + (size_t)r * 38 * 256;

  float4 vs = make_float4(0.f, 0.f, 0.f, 0.f);
#pragma unroll 1
  for (int j = 0; j < 29; ++j) {
    float4 p = pair_log(zr, t + j, lane);
    vs.x += p.x; vs.y += p.y; vs.z += p.z; vs.w += p.w;
  }
  *reinterpret_cast<float4*>(VSUM + (size_t)r * 256 + lane * 4) = vs;

  float4 fl = logmap0_col(zr, t + 29, lane);   // z_last
  float4 fp = logmap0_col(zr, t + 28, lane);   // z_prev
  const size_t fb = (size_t)r * 768 + lane * 4;
  store_hi4(Fh, fb, fl);
  store_hi4(Fh, fb + 256, fp);
  const float s29 = 1.f / 29.f;
  float4 o;
  o.x = vs.x * s29; o.y = vs.y * s29; o.z = vs.z * s29; o.w = vs.w * s29;
  store_hi4(Fh, fb + 512, o);
}

// --------- fused: z_next = expmap(z_last, sum VP + b3); then (if t<7)
// incremental velocity + FEAT for step t+1.
__global__ __launch_bounds__(256) void expmap_vel_fused_k(
    float* __restrict__ Z, const float* __restrict__ VP,
    const float* __restrict__ b3, unsigned short* __restrict__ Fh,
    float* __restrict__ VSUM, int t)
{
  const int r = blockIdx.x * 4 + (threadIdx.x >> 6);
  const int lane = threadIdx.x & 63;
  float* zr = Z + (size_t)r * 38 * 256;
  float4 x = *reinterpret_cast<const float4*>(zr + (size_t)(t + 29) * 256 + lane * 4);
  float4 v = *reinterpret_cast<const float4*>(b3 + lane * 4);
#pragma unroll
  for (int p = 0; p < 4; ++p) {
    float4 a = *reinterpret_cast<const float4*>(
        VP + (size_t)p * 655360u + (size_t)r * 256 + lane * 4);
    v.x += a.x; v.y += a.y; v.z += a.z; v.w += a.w;
  }
  float x2 = wave_sum(x.x * x.x + x.y * x.y + x.z * x.z + x.w * x.w);
  float v2 = wave_sum(v.x * v.x + v.y * v.y + v.z * v.z + v.w * v.w);
  float xv = wave_sum(x.x * v.x + x.y * v.y + x.z * v.z + x.w * v.w);

  float vn = fmaxf(sqrtf(v2), EPS_F);
  float lamx = 2.f / fmaxf(1.f - x2, EPS_F);
  float s = tanhf(0.5f * lamx * vn) / vn;
  float xy = s * xv;
  float y2 = s * s * v2;
  float a  = 1.f + 2.f * xy + y2;
  float bb = 1.f - x2;
  float den = fmaxf(1.f + 2.f * xy + x2 * y2, EPS_F);
  float inv = 1.f / den;
  float4 res;
  res.x = (a * x.x + bb * s * v.x) * inv;
  res.y = (a * x.y + bb * s * v.y) * inv;
  res.z = (a * x.z + bb * s * v.z) * inv;
  res.w = (a * x.w + bb * s * v.w) * inv;
  float r2 = wave_sum(res.x * res.x + res.y * res.y + res.z * res.z + res.w * res.w);
  float rn = sqrtf(r2);
  if (rn > MAX_NORM_F) {
    float sc = MAX_NORM_F / fmaxf(rn, EPS_F);
    res.x *= sc; res.y *= sc; res.z *= sc; res.w *= sc;
    r2 = MAX_NORM_F * MAX_NORM_F;
    rn = MAX_NORM_F;
  }
  *reinterpret_cast<float4*>(zr + (size_t)(t + 30) * 256 + lane * 4) = res;

  if (t < 7) {
    float4 pm = pair_log(zr, t, lane);
    float xyn = wave_sum(x.x * res.x + x.y * res.y + x.z * res.z + x.w * res.w);
    float an  = 1.f - 2.f * xyn + r2;
    float bbn = 1.f - x2;
    float denn = fmaxf(1.f - 2.f * xyn + x2 * r2, EPS_F);
    float invn = 1.f / denn;
    float4 u;
    u.x = (bbn * res.x - an * x.x) * invn;
    u.y = (bbn * res.y - an * x.y) * invn;
    u.z = (bbn * res.z - an * x.z) * invn;
    u.w = (bbn * res.w - an * x.w) * invn;
    float u2 = wave_sum(u.x * u.x + u.y * u.y + u.z * u.z + u.w * u.w);
    float un = fmaxf(sqrtf(u2), EPS_F);
    float coef = fmaxf(1.f - x2, EPS_F) * atanhf(fminf(un, 1.f - 1e-7f)) / un;
    float4 vs = *reinterpret_cast<const float4*>(VSUM + (size_t)r * 256 + lane * 4);
    vs.x += coef * u.x - pm.x; vs.y += coef * u.y - pm.y;
    vs.z += coef * u.z - pm.z; vs.w += coef * u.w - pm.w;
    *reinterpret_cast<float4*>(VSUM + (size_t)r * 256 + lane * 4) = vs;

    float rnp = fmaxf(rn, EPS_F);
    float cl = atanhf(fminf(rnp, 1.f - 1e-7f)) / rnp;
    float nx = fmaxf(sqrtf(x2), EPS_F);
    float cp = atanhf(fminf(nx, 1.f - 1e-7f)) / nx;
    const size_t fb = (size_t)r * 768 + lane * 4;
    float4 o;
    o.x = cl * res.x; o.y = cl * res.y; o.z = cl * res.z; o.w = cl * res.w;
    store_hi4(Fh, fb, o);
    o.x = cp * x.x; o.y = cp * x.y; o.z = cp * x.z; o.w = cp * x.w;
    store_hi4(Fh, fb + 256, o);
    const float s29 = 1.f / 29.f;
    o.x = vs.x * s29; o.y = vs.y * s29; o.z = vs.z * s29; o.w = vs.w * s29;
    store_hi4(Fh, fb + 512, o);
  }
}

// -------------------------- logmap0 over appended cols, bf16-hi out
__global__ __launch_bounds__(256) void logmap0_rows_k(
    const float* __restrict__ Z, unsigned short* __restrict__ Uh)
{
  const int q = blockIdx.x * 4 + (threadIdx.x >> 6);
  const int lane = threadIdx.x & 63;
  const int r = q >> 3;
  const int tt = q & 7;
  float4 o = logmap0_col(Z + (size_t)r * 38 * 256, 30 + tt, lane);
  store_hi4(Uh, (size_t)q * 256 + lane * 4, o);
}

// ---------------------------------------------------------------- launcher
extern "C" void kernel_launch(void* const* d_in, const int* in_sizes, int n_in,
                              void* d_out, int out_size, void* d_ws, size_t ws_size,
                              hipStream_t stream)
{
  const float* c0 = (const float*)d_in[0];
  const float* c1 = (const float*)d_in[1];
  const float* c2 = (const float*)d_in[2];
  const float* c3 = (const float*)d_in[3];
  const float* W_embed = (const float*)d_in[4];
  const float* b_embed = (const float*)d_in[5];
  const float* ln_g    = (const float*)d_in[6];
  const float* ln_b    = (const float*)d_in[7];
  const float* W1 = (const float*)d_in[8];
  const float* b1 = (const float*)d_in[9];
  const float* W2 = (const float*)d_in[10];
  const float* b2 = (const float*)d_in[11];
  const float* W3 = (const float*)d_in[12];
  const float* b3 = (const float*)d_in[13];
  const float* W_out = (const float*)d_in[14];
  const float* b_out = (const float*)d_in[15];
  float* out = (float*)d_out;
  float* ws  = (float*)d_ws;

  // ---- ws layout. Peak identical to R9 (proven).
  float* Z = ws;
  unsigned short* Abf = (unsigned short*)ws;        // [61440][512] bf16 (aliases Z)
  unsigned short* Rs = (unsigned short*)(ws + 24903680u);
  unsigned short* TAN = Rs + 20000000u;             // 4*15360*256 shorts
  unsigned short* W1h = Rs;                         // [1024][768]
  unsigned short* W1l = Rs + 786432u;
  unsigned short* W2h = Rs + 1572864u;              // [1024][1024]
  unsigned short* W2l = Rs + 2621440u;
  unsigned short* W3h = Rs + 3670016u;              // [256][1024]
  unsigned short* W3l = Rs + 3932160u;
  unsigned short* Woh = Rs + 4194304u;              // [504][256]
  unsigned short* Wol = Rs + 4323328u;
  unsigned short* FEATh = Rs + 4452352u;            // [2560][768]
  unsigned short* H1h = Rs + 6418432u;              // [2560][1024]
  unsigned short* H2h = Rs + 9039872u;              // [2560][1024]
  unsigned short* Uh  = Rs + 11661312u;             // [20480][256] (stage C)
  float* VP   = ws + 34338816u;                     // 4 x 2560*256 parts
  float* VSUM = ws + 39581696u;                     // 2560*256

  unsigned short* EW = (unsigned short*)d_out;      // embed weights scratch

  dim3 blk(256);

  // Stage A: A->bf16 pre-pass + embed weight split -> embed GEMM -> LN
  c2bf_k<<<dim3(15360), blk, 0, stream>>>(c0, c1, c2, c3, Abf);
  {
    WS4 d;
    for (int c = 0; c < 4; ++c) {
      d.W[c] = W_embed + (size_t)c * 504 * 256;
      d.Th[c] = EW + (size_t)c * 262144u;
      d.Tl[c] = EW + (size_t)c * 262144u + 131072u;
      d.K[c] = 504; d.N[c] = 256; d.Kp[c] = 512;
    }
    wsplit_all_k<<<dim3(4, 8, 4), blk, 0, stream>>>(d);
  }
  gemm_embed2<<<dim3(480, 2), blk, 0, stream>>>(Abf, EW, b_embed, TAN);
  ln_expmap0_k<<<dim3(3840), blk, 0, stream>>>(TAN, ln_g, ln_b, Z);

  // MLP/out weight splits in one launch
  {
    WS4 d;
    d.W[0] = W1;    d.Th[0] = W1h; d.Tl[0] = W1l; d.K[0] = 768;  d.N[0] = 1024; d.Kp[0] = 768;
    d.W[1] = W2;    d.Th[1] = W2h; d.Tl[1] = W2l; d.K[1] = 1024; d.N[1] = 1024; d.Kp[1] = 1024;
    d.W[2] = W3;    d.Th[2] = W3h; d.Tl[2] = W3l; d.K[2] = 1024; d.N[2] = 256;  d.Kp[2] = 1024;
    d.W[3] = W_out; d.Th[3] = Woh; d.Tl[3] = Wol; d.K[3] = 256;  d.N[3] = 504;  d.Kp[3] = 256;
    wsplit_all_k<<<dim3(16, 16, 4), blk, 0, stream>>>(d);
  }

  // Stage B: 8 recurrent steps (x1 MLP weights; velocity/feat fused)
  vel_feat_inc_k<<<dim3(640), blk, 0, stream>>>(Z, FEATh, VSUM, 0);
  for (int t = 0; t < 8; ++t) {
    gemm_n64_x1<<<dim3(20, 16, 1), blk, 0, stream>>>(
        FEATh, 768, W1h, 768, b1, nullptr, H1h,
        1024, 2560, 1024, 768, 768, 1);
    gemm_n64_x1<<<dim3(20, 16, 1), blk, 0, stream>>>(
        H1h, 1024, W2h, 1024, b2, nullptr, H2h,
        1024, 2560, 1024, 1024, 1024, 1);
    gemm_n64_x1<<<dim3(20, 4, 4), blk, 0, stream>>>(
        H2h, 1024, W3h, 1024, nullptr, VP, nullptr,
        256, 2560, 256, 1024, 256, 0);
    expmap_vel_fused_k<<<dim3(640), blk, 0, stream>>>(
        Z, VP, b3, FEATh, VSUM, t);
  }

  // Stage C: logmap0 -> final projection into d_out (W_out stays x2)
  logmap0_rows_k<<<dim3(5120), blk, 0, stream>>>(Z, Uh);
  gemm_n64_x2<<<dim3(160, 8, 1), blk, 0, stream>>>(
      Uh, 256, Woh, Wol, 256, b_out, out, nullptr,
      504, 20480, 504, 256, 256, 0);
}

// Round 11
// 573.001 us; speedup vs baseline: 1.6446x; 1.0353x over previous
//
#include <hip/hip_runtime.h>
#include <cstddef>
#include <cstdint>

#define EPS_F 1e-7f
#define MAX_NORM_F 0.99999f   // (1 - 1e-5) / SC, SC = 1

typedef __attribute__((ext_vector_type(8))) short bf16x8;  // 8 bf16 (4 VGPR)
typedef __attribute__((ext_vector_type(4))) float f32x4;

// ---------------------------------------------------------------- helpers
__device__ __forceinline__ unsigned short f2bf(float x) {
  unsigned int u = __float_as_uint(x);
  unsigned int r = u + 0x7FFFu + ((u >> 16) & 1u);   // RNE (no NaN in data)
  return (unsigned short)(r >> 16);
}
__device__ __forceinline__ float bf2f(unsigned short h) {
  return __uint_as_float(((unsigned int)h) << 16);
}

__device__ __forceinline__ float wave_sum(float v) {
#pragma unroll
  for (int off = 32; off; off >>= 1) v += __shfl_xor(v, off);
  return v;
}

__device__ __forceinline__ void store_hi4(unsigned short* H, size_t idx, float4 v) {
  ushort4 h;
  h.x = f2bf(v.x); h.y = f2bf(v.y); h.z = f2bf(v.z); h.w = f2bf(v.w);
  *reinterpret_cast<ushort4*>(H + idx) = h;
}

// async global->LDS, 16B per lane; LDS dest = uniform base + lane*16
__device__ __forceinline__ void gl_lds16(const unsigned short* g, unsigned short* l) {
  __builtin_amdgcn_global_load_lds(
      (const __attribute__((address_space(1))) void*)g,
      (__attribute__((address_space(3))) void*)l, 16, 0, 0);
}

// fragment read offset (elements) for logical row r, k-group kg, tile base tb
__device__ __forceinline__ int frag_off(int tb, int r, int kg) {
  return tb + r * 32 + ((kg ^ ((r >> 1) & 3)) << 3);
}

// ------------------------------- A fp32 -> bf16 pre-pass (stacked, padded)
__global__ __launch_bounds__(256) void c2bf_k(
    const float* __restrict__ A0, const float* __restrict__ A1,
    const float* __restrict__ A2, const float* __restrict__ A3,
    unsigned short* __restrict__ Abf)
{
  const int row = blockIdx.x * 4 + (threadIdx.x >> 6);   // 0..61439
  const int lane = threadIdx.x & 63;
  const int c = row / 15360;
  const int lr = row - c * 15360;
  const float* A = (c == 0) ? A0 : (c == 1) ? A1 : (c == 2) ? A2 : A3;

  float4 f0 = make_float4(0.f, 0.f, 0.f, 0.f), f1 = f0;
  if (lane < 63) {
    const float* p = A + (size_t)lr * 504 + lane * 8;
    f0 = *reinterpret_cast<const float4*>(p);
    f1 = *reinterpret_cast<const float4*>(p + 4);
  }
  bf16x8 o;
  o[0] = (short)f2bf(f0.x); o[1] = (short)f2bf(f0.y);
  o[2] = (short)f2bf(f0.z); o[3] = (short)f2bf(f0.w);
  o[4] = (short)f2bf(f1.x); o[5] = (short)f2bf(f1.y);
  o[6] = (short)f2bf(f1.z); o[7] = (short)f2bf(f1.w);
  *reinterpret_cast<bf16x8*>(Abf + (size_t)row * 512 + lane * 8) = o;
}

// --------------------------------------------- weight transpose+split pass
struct WS4 {
  const float* W[4];
  unsigned short* Th[4];
  unsigned short* Tl[4];
  int K[4], N[4], Kp[4];
};

__global__ __launch_bounds__(256) void wsplit_all_k(WS4 d) {
  const int zi = blockIdx.z;
  const float* W = d.W[zi];
  unsigned short* Th = d.Th[zi];
  unsigned short* Tl = d.Tl[zi];
  const int K = d.K[zi], N = d.N[zi], Kp = d.Kp[zi];
  const int n0 = blockIdx.x * 64, k0 = blockIdx.y * 64;
  if (n0 >= N || k0 >= Kp) return;

  __shared__ float T[64][65];
  const int t = threadIdx.x;
  {
    const int lk = t >> 2;
    const int ln = (t & 3) * 16;
    const int gk = k0 + lk;
#pragma unroll
    for (int j = 0; j < 16; j += 4) {
      float4 v = make_float4(0.f, 0.f, 0.f, 0.f);
      const int gn = n0 + ln + j;
      if (gk < K) {
        if (gn + 3 < N) {
          v = *reinterpret_cast<const float4*>(W + (size_t)gk * N + gn);
        } else {
          const float* p = W + (size_t)gk * N;
          if (gn     < N) v.x = p[gn];
          if (gn + 1 < N) v.y = p[gn + 1];
          if (gn + 2 < N) v.z = p[gn + 2];
          if (gn + 3 < N) v.w = p[gn + 3];
        }
      }
      T[lk][ln + j + 0] = v.x; T[lk][ln + j + 1] = v.y;
      T[lk][ln + j + 2] = v.z; T[lk][ln + j + 3] = v.w;
    }
  }
  __syncthreads();
  {
    const int rn = t >> 2;
    const int rk = (t & 3) * 16;
    const int gn = n0 + rn;
    if (gn < N) {
      size_t base = (size_t)gn * Kp + k0 + rk;
#pragma unroll
      for (int j = 0; j < 16; ++j) {
        float x = T[rk + j][rn];
        unsigned short h = f2bf(x);
        unsigned short l = f2bf(x - bf2f(h));
        Th[base + j] = h;
        Tl[base + j] = l;
      }
    }
  }
}

// --------------------------------------------------- MLP GEMM: x1, 128x64
// acc += Ah*Bh (bf16-hi activations AND weights). gl_lds staging,
// double-buffered 24KB LDS, 1 barrier/iter, prefetch-early.
__global__ __launch_bounds__(256) void gemm_n64_x1(
    const unsigned short* __restrict__ Ah, int lda,
    const unsigned short* __restrict__ Bh, int ldb,
    const float* __restrict__ bias, float* __restrict__ Cf,
    unsigned short* __restrict__ Ch,
    int ldc, int M, int N, int Ktot, int kslice, int relu)
{
  __shared__ unsigned short sm[12288];   // 2 x (Ah@0 Bh@4096)

  const int t = threadIdx.x;
  const int bm = blockIdx.x * 128;
  const int bn = blockIdx.y * 64;
  const int z  = blockIdx.z;
  const int koff = z * kslice;
  const int klen = min(kslice, Ktot - koff);

  const int lane = t & 63, wave = t >> 6;
  const int wm = (wave >> 1) * 64, wn = (wave & 1) * 32;
  const int fr = lane & 15, kg = lane >> 4;

  const unsigned short* sp[3];
  int dpo[3];
#pragma unroll
  for (int q = 0; q < 3; ++q) {
    const int j = wave + 4 * q;
    int tile, i;
    if (j < 8) { tile = 0; i = j; }
    else       { tile = 1; i = j - 8; }
    const int row = i * 16 + (lane >> 2);
    const int chunk = (lane & 3) ^ ((row >> 1) & 3);
    const unsigned short* base = (tile == 0) ? Ah : Bh;
    const int ld = (tile == 0) ? lda : ldb;
    const int grow = (tile == 0) ? (bm + row) : min(bn + row, N - 1);
    const int tb = (tile == 0) ? 0 : 4096;
    sp[q] = base + (size_t)grow * ld + koff + chunk * 8;
    dpo[q] = tb + i * 512 + lane * 8;
  }

  int offA[4], offB[2];
#pragma unroll
  for (int i = 0; i < 4; ++i) offA[i] = frag_off(0, wm + i * 16 + fr, kg);
#pragma unroll
  for (int i = 0; i < 2; ++i) offB[i] = frag_off(4096, wn + i * 16 + fr, kg);

  f32x4 acc[4][2] = {};
#pragma unroll
  for (int q = 0; q < 3; ++q) gl_lds16(sp[q], sm + dpo[q]);

  int cur = 0;
  for (int k0 = 0; k0 < klen; k0 += 32) {
    __syncthreads();                     // buf[cur] staged
    if (k0 + 32 < klen) {
      unsigned short* nb = sm + (cur ^ 1) * 6144;
#pragma unroll
      for (int q = 0; q < 3; ++q) { sp[q] += 32; gl_lds16(sp[q], nb + dpo[q]); }
    }
    const unsigned short* s = sm + cur * 6144;
    bf16x8 ah[4], bh[2];
#pragma unroll
    for (int i = 0; i < 4; ++i)
      ah[i] = *reinterpret_cast<const bf16x8*>(s + offA[i]);
#pragma unroll
    for (int i = 0; i < 2; ++i)
      bh[i] = *reinterpret_cast<const bf16x8*>(s + offB[i]);
#pragma unroll
    for (int mi = 0; mi < 4; ++mi)
#pragma unroll
      for (int ni = 0; ni < 2; ++ni)
        acc[mi][ni] = __builtin_amdgcn_mfma_f32_16x16x32_bf16(ah[mi], bh[ni], acc[mi][ni], 0, 0, 0);
    cur ^= 1;
  }

#pragma unroll
  for (int mi = 0; mi < 4; ++mi) {
#pragma unroll
    for (int ni = 0; ni < 2; ++ni) {
      const int col = bn + wn + ni * 16 + fr;
      if (col >= N) continue;
      const int row0 = bm + wm + mi * 16 + kg * 4;
      const float bv = bias ? bias[col] : 0.f;
      if (Cf) {
        float* Cz = Cf + (size_t)z * (size_t)M * (size_t)N;
#pragma unroll
        for (int r = 0; r < 4; ++r) {
          float v = acc[mi][ni][r] + bv;
          if (relu) v = fmaxf(v, 0.f);
          Cz[(size_t)(row0 + r) * ldc + col] = v;
        }
      } else {
#pragma unroll
        for (int r = 0; r < 4; ++r) {
          float v = acc[mi][ni][r] + bv;
          if (relu) v = fmaxf(v, 0.f);
          Ch[(size_t)(row0 + r) * ldc + col] = f2bf(v);
        }
      }
    }
  }
}

// --------------------------------------------------- GEMM: x2, 128x64
// acc += Ah*Bh + Ah*Bl (split weights). Used for the final W_out GEMM.
__global__ __launch_bounds__(256) void gemm_n64_x2(
    const unsigned short* __restrict__ Ah, int lda,
    const unsigned short* __restrict__ Bh, const unsigned short* __restrict__ Bl,
    int ldb,
    const float* __restrict__ bias, float* __restrict__ Cf,
    unsigned short* __restrict__ Ch,
    int ldc, int M, int N, int Ktot, int kslice, int relu)
{
  __shared__ unsigned short sm[16384];   // 2 x (Ah@0 Bh@4096 Bl@6144)

  const int t = threadIdx.x;
  const int bm = blockIdx.x * 128;
  const int bn = blockIdx.y * 64;
  const int z  = blockIdx.z;
  const int koff = z * kslice;
  const int klen = min(kslice, Ktot - koff);

  const int lane = t & 63, wave = t >> 6;
  const int wm = (wave >> 1) * 64, wn = (wave & 1) * 32;
  const int fr = lane & 15, kg = lane >> 4;

  const unsigned short* sp[4];
  int dpo[4];
#pragma unroll
  for (int q = 0; q < 4; ++q) {
    const int j = wave + 4 * q;
    int tile, i;
    if (j < 8)       { tile = 0; i = j; }
    else if (j < 12) { tile = 1; i = j - 8; }
    else             { tile = 2; i = j - 12; }
    const int row = i * 16 + (lane >> 2);
    const int chunk = (lane & 3) ^ ((row >> 1) & 3);
    const unsigned short* base = (tile == 0) ? Ah : (tile == 1) ? Bh : Bl;
    const int ld = (tile == 0) ? lda : ldb;
    const int grow = (tile == 0) ? (bm + row) : min(bn + row, N - 1);
    const int tb = (tile == 0) ? 0 : (tile == 1) ? 4096 : 6144;
    sp[q] = base + (size_t)grow * ld + koff + chunk * 8;
    dpo[q] = tb + i * 512 + lane * 8;
  }

  int offA[4], offB[2];
#pragma unroll
  for (int i = 0; i < 4; ++i) offA[i] = frag_off(0, wm + i * 16 + fr, kg);
#pragma unroll
  for (int i = 0; i < 2; ++i) offB[i] = frag_off(4096, wn + i * 16 + fr, kg);

  f32x4 acc[4][2] = {};
#pragma unroll
  for (int q = 0; q < 4; ++q) gl_lds16(sp[q], sm + dpo[q]);

  int cur = 0;
  for (int k0 = 0; k0 < klen; k0 += 32) {
    __syncthreads();
    if (k0 + 32 < klen) {
      unsigned short* nb = sm + (cur ^ 1) * 8192;
#pragma unroll
      for (int q = 0; q < 4; ++q) { sp[q] += 32; gl_lds16(sp[q], nb + dpo[q]); }
    }
    const unsigned short* s = sm + cur * 8192;
    bf16x8 ah[4], bh[2], bl[2];
#pragma unroll
    for (int i = 0; i < 4; ++i)
      ah[i] = *reinterpret_cast<const bf16x8*>(s + offA[i]);
#pragma unroll
    for (int i = 0; i < 2; ++i) {
      bh[i] = *reinterpret_cast<const bf16x8*>(s + offB[i]);
      bl[i] = *reinterpret_cast<const bf16x8*>(s + offB[i] + 2048);
    }
#pragma unroll
    for (int mi = 0; mi < 4; ++mi)
#pragma unroll
      for (int ni = 0; ni < 2; ++ni)
        acc[mi][ni] = __builtin_amdgcn_mfma_f32_16x16x32_bf16(ah[mi], bh[ni], acc[mi][ni], 0, 0, 0);
#pragma unroll
    for (int mi = 0; mi < 4; ++mi)
#pragma unroll
      for (int ni = 0; ni < 2; ++ni)
        acc[mi][ni] = __builtin_amdgcn_mfma_f32_16x16x32_bf16(ah[mi], bl[ni], acc[mi][ni], 0, 0, 0);
    cur ^= 1;
  }

#pragma unroll
  for (int mi = 0; mi < 4; ++mi) {
#pragma unroll
    for (int ni = 0; ni < 2; ++ni) {
      const int col = bn + wn + ni * 16 + fr;
      if (col >= N) continue;
      const int row0 = bm + wm + mi * 16 + kg * 4;
      const float bv = bias ? bias[col] : 0.f;
      if (Cf) {
        float* Cz = Cf + (size_t)z * (size_t)M * (size_t)N;
#pragma unroll
        for (int r = 0; r < 4; ++r) {
          float v = acc[mi][ni][r] + bv;
          if (relu) v = fmaxf(v, 0.f);
          Cz[(size_t)(row0 + r) * ldc + col] = v;
        }
      } else {
#pragma unroll
        for (int r = 0; r < 4; ++r) {
          float v = acc[mi][ni][r] + bv;
          if (relu) v = fmaxf(v, 0.f);
          Ch[(size_t)(row0 + r) * ldc + col] = f2bf(v);
        }
      }
    }
  }
}

// ---- embed GEMM: x1 (Ah*Bh), all-bf16, all-gl_lds, 128x128 tile,
// dbuf 32KB LDS, 1 barrier/iter. A = Abf[61440][512]; TAN bf16-hi out.
__global__ __launch_bounds__(256) void gemm_embed1(
    const unsigned short* __restrict__ Abf, const unsigned short* __restrict__ EW,
    const float* __restrict__ b_embed, unsigned short* __restrict__ TAN)
{
  __shared__ unsigned short sm[16384];   // 2 x (Ah@0 Bh@4096)

  const int t = threadIdx.x;
  const int bx = blockIdx.x;
  const int bm = bx * 128;               // global row into Abf/TAN
  const int bn = blockIdx.y * 128;       // 0 or 128
  const int c  = bx / 120;
  const unsigned short* Bh = EW + (size_t)c * 262144u;
  const float* bias = b_embed + c * 256;

  const int lane = t & 63, wave = t >> 6;
  const int wm = (wave >> 1) * 64, wn = (wave & 1) * 64;
  const int fr = lane & 15, kg = lane >> 4;

  // 16 wave-issues: tile = j>>3 (0 A, 1 Bh), i = j&7; j = wave + 4q
  const unsigned short* sp[4];
  int dpo[4];
#pragma unroll
  for (int q = 0; q < 4; ++q) {
    const int j = wave + 4 * q;
    const int tile = j >> 3;
    const int i = j & 7;
    const int row = i * 16 + (lane >> 2);
    const int chunk = (lane & 3) ^ ((row >> 1) & 3);
    const unsigned short* base = (tile == 0) ? Abf : Bh;
    const int grow = (tile == 0) ? (bm + row) : (bn + row);
    const int tb = tile * 4096;
    sp[q] = base + (size_t)grow * 512 + chunk * 8;
    dpo[q] = tb + i * 512 + lane * 8;
  }

  int offA[4], offB[4];
#pragma unroll
  for (int i = 0; i < 4; ++i) {
    offA[i] = frag_off(0,    wm + i * 16 + fr, kg);
    offB[i] = frag_off(4096, wn + i * 16 + fr, kg);
  }

  f32x4 acc[4][4] = {};
#pragma unroll
  for (int q = 0; q < 4; ++q) gl_lds16(sp[q], sm + dpo[q]);

  int cur = 0;
  for (int k0 = 0; k0 < 512; k0 += 32) {
    __syncthreads();                     // buf[cur] staged (vmcnt drained)
    if (k0 + 32 < 512) {
      unsigned short* nb = sm + (cur ^ 1) * 8192;
#pragma unroll
      for (int q = 0; q < 4; ++q) { sp[q] += 32; gl_lds16(sp[q], nb + dpo[q]); }
    }
    const unsigned short* s = sm + cur * 8192;
    bf16x8 ah[4], bh[4];
#pragma unroll
    for (int i = 0; i < 4; ++i) {
      ah[i] = *reinterpret_cast<const bf16x8*>(s + offA[i]);
      bh[i] = *reinterpret_cast<const bf16x8*>(s + offB[i]);
    }
#pragma unroll
    for (int mi = 0; mi < 4; ++mi)
#pragma unroll
      for (int ni = 0; ni < 4; ++ni)
        acc[mi][ni] = __builtin_amdgcn_mfma_f32_16x16x32_bf16(ah[mi], bh[ni], acc[mi][ni], 0, 0, 0);
    cur ^= 1;
  }

#pragma unroll
  for (int mi = 0; mi < 4; ++mi) {
#pragma unroll
    for (int ni = 0; ni < 4; ++ni) {
      const int col = bn + wn + ni * 16 + fr;
      const int row0 = bm + wm + mi * 16 + kg * 4;
      const float bv = bias[col];
#pragma unroll
      for (int r = 0; r < 4; ++r)
        TAN[(size_t)(row0 + r) * 256 + col] = f2bf(acc[mi][ni][r] + bv);
    }
  }
}

// ------------------------ LayerNorm + expmap0 -> Z (wave/row, bf16 TAN in)
__global__ __launch_bounds__(256) void ln_expmap0_k(
    const unsigned short* __restrict__ TAN, const float* __restrict__ gamma,
    const float* __restrict__ beta, float* __restrict__ Z)
{
  const int row = blockIdx.x * 4 + (threadIdx.x >> 6);   // b*30 + n
  const int lane = threadIdx.x & 63;
  const int b = row / 30;
  const int n = row % 30;

  float4 tc[4];
  float4 ts = make_float4(0.f, 0.f, 0.f, 0.f);
#pragma unroll
  for (int c = 0; c < 4; ++c) {
    ushort4 xu = *reinterpret_cast<const ushort4*>(
        TAN + ((size_t)c * 15360 + row) * 256 + lane * 4);
    float4 x = make_float4(bf2f(xu.x), bf2f(xu.y), bf2f(xu.z), bf2f(xu.w));
    float mu = wave_sum(x.x + x.y + x.z + x.w) * (1.f / 256.f);
    float4 xm = make_float4(x.x - mu, x.y - mu, x.z - mu, x.w - mu);
    float var = wave_sum(xm.x * xm.x + xm.y * xm.y + xm.z * xm.z + xm.w * xm.w)
                * (1.f / 256.f);
    float rs = rsqrtf(var + 1e-5f);
    float4 g = *reinterpret_cast<const float4*>(gamma + c * 256 + lane * 4);
    float4 be = *reinterpret_cast<const float4*>(beta + c * 256 + lane * 4);
    float4 tv = make_float4(xm.x * rs * g.x + be.x, xm.y * rs * g.y + be.y,
                            xm.z * rs * g.z + be.z, xm.w * rs * g.w + be.w);
    tc[c] = tv;
    ts.x += tv.x; ts.y += tv.y; ts.z += tv.z; ts.w += tv.w;
  }
#pragma unroll
  for (int g5 = 0; g5 < 5; ++g5) {
    float4 v = (g5 == 0) ? ts : tc[g5 - 1];
    float n2 = wave_sum(v.x * v.x + v.y * v.y + v.z * v.z + v.w * v.w);
    float nn = fmaxf(sqrtf(n2), EPS_F);
    float th = tanhf(nn);
    float w = th / nn;
    if (th > MAX_NORM_F) w *= MAX_NORM_F / fmaxf(th, EPS_F);
    float4 o = make_float4(v.x * w, v.y * w, v.z * w, v.w * w);
    *reinterpret_cast<float4*>(
        Z + (((size_t)g5 * 512 + b) * 38 + n) * 256 + lane * 4) = o;
  }
}

// ------------------------------------------------ per-pair logmap (1 wave)
__device__ __forceinline__ float4 pair_log(const float* zr, int c, int lane) {
  float4 x = *reinterpret_cast<const float4*>(zr + (size_t)c * 256 + lane * 4);
  float4 y = *reinterpret_cast<const float4*>(zr + (size_t)(c + 1) * 256 + lane * 4);
  float x2 = wave_sum(x.x * x.x + x.y * x.y + x.z * x.z + x.w * x.w);
  float y2 = wave_sum(y.x * y.x + y.y * y.y + y.z * y.z + y.w * y.w);
  float xy = wave_sum(x.x * y.x + x.y * y.y + x.z * y.z + x.w * y.w);
  float a  = 1.f - 2.f * xy + y2;
  float bb = 1.f - x2;
  float den = fmaxf(1.f - 2.f * xy + x2 * y2, EPS_F);
  float inv = 1.f / den;
  float4 u;
  u.x = (bb * y.x - a * x.x) * inv;
  u.y = (bb * y.y - a * x.y) * inv;
  u.z = (bb * y.z - a * x.z) * inv;
  u.w = (bb * y.w - a * x.w) * inv;
  float u2 = wave_sum(u.x * u.x + u.y * u.y + u.z * u.z + u.w * u.w);
  float un = fmaxf(sqrtf(u2), EPS_F);
  float coef = fmaxf(1.f - x2, EPS_F) * atanhf(fminf(un, 1.f - 1e-7f)) / un;
  float4 o;
  o.x = coef * u.x; o.y = coef * u.y; o.z = coef * u.z; o.w = coef * u.w;
  return o;
}

__device__ __forceinline__ float4 logmap0_col(const float* zr, int c, int lane) {
  float4 z = *reinterpret_cast<const float4*>(zr + (size_t)c * 256 + lane * 4);
  float z2 = wave_sum(z.x * z.x + z.y * z.y + z.z * z.z + z.w * z.w);
  float nz = fmaxf(sqrtf(z2), EPS_F);
  float cc = atanhf(fminf(nz, 1.f - 1e-7f)) / nz;
  float4 o;
  o.x = cc * z.x; o.y = cc * z.y; o.z = cc * z.z; o.w = cc * z.w;
  return o;
}

// -------- velocity t=0: 4 waves per row, pairs split across waves.
// wave w handles pairs j = w, w+4, ...; LDS combine; waves 1/2 do the
// two logmap0 feature columns concurrently with wave 0's combine.
__global__ __launch_bounds__(256) void vel_feat_t0_k(
    const float* __restrict__ Z, unsigned short* __restrict__ Fh,
    float* __restrict__ VSUM)
{
  __shared__ float red[4][256];
  const int r = blockIdx.x;
  const int wave = threadIdx.x >> 6, lane = threadIdx.x & 63;
  const float* zr = Z + (size_t)r * 38 * 256;

  float4 vs = make_float4(0.f, 0.f, 0.f, 0.f);
  for (int j = wave; j < 29; j += 4) {
    float4 p = pair_log(zr, j, lane);
    vs.x += p.x; vs.y += p.y; vs.z += p.z; vs.w += p.w;
  }
  *reinterpret_cast<float4*>(&red[wave][lane * 4]) = vs;
  __syncthreads();

  const size_t fb = (size_t)r * 768 + lane * 4;
  if (wave == 0) {
    float4 a0 = *reinterpret_cast<const float4*>(&red[0][lane * 4]);
    float4 a1 = *reinterpret_cast<const float4*>(&red[1][lane * 4]);
    float4 a2 = *reinterpret_cast<const float4*>(&red[2][lane * 4]);
    float4 a3 = *reinterpret_cast<const float4*>(&red[3][lane * 4]);
    vs.x = a0.x + a1.x + a2.x + a3.x;
    vs.y = a0.y + a1.y + a2.y + a3.y;
    vs.z = a0.z + a1.z + a2.z + a3.z;
    vs.w = a0.w + a1.w + a2.w + a3.w;
    *reinterpret_cast<float4*>(VSUM + (size_t)r * 256 + lane * 4) = vs;
    const float s29 = 1.f / 29.f;
    float4 o;
    o.x = vs.x * s29; o.y = vs.y * s29; o.z = vs.z * s29; o.w = vs.w * s29;
    store_hi4(Fh, fb + 512, o);
  } else if (wave == 1) {
    float4 fl = logmap0_col(zr, 29, lane);   // z_last
    store_hi4(Fh, fb, fl);
  } else if (wave == 2) {
    float4 fp = logmap0_col(zr, 28, lane);   // z_prev
    store_hi4(Fh, fb + 256, fp);
  }
}

// --------- fused: z_next = expmap(z_last, sum VP + b3); then (if t<7)
// incremental velocity + FEAT for step t+1.
__global__ __launch_bounds__(256) void expmap_vel_fused_k(
    float* __restrict__ Z, const float* __restrict__ VP,
    const float* __restrict__ b3, unsigned short* __restrict__ Fh,
    float* __restrict__ VSUM, int t)
{
  const int r = blockIdx.x * 4 + (threadIdx.x >> 6);
  const int lane = threadIdx.x & 63;
  float* zr = Z + (size_t)r * 38 * 256;
  float4 x = *reinterpret_cast<const float4*>(zr + (size_t)(t + 29) * 256 + lane * 4);
  float4 v = *reinterpret_cast<const float4*>(b3 + lane * 4);
#pragma unroll
  for (int p = 0; p < 4; ++p) {
    float4 a = *reinterpret_cast<const float4*>(
        VP + (size_t)p * 655360u + (size_t)r * 256 + lane * 4);
    v.x += a.x; v.y += a.y; v.z += a.z; v.w += a.w;
  }
  float x2 = wave_sum(x.x * x.x + x.y * x.y + x.z * x.z + x.w * x.w);
  float v2 = wave_sum(v.x * v.x + v.y * v.y + v.z * v.z + v.w * v.w);
  float xv = wave_sum(x.x * v.x + x.y * v.y + x.z * v.z + x.w * v.w);

  float vn = fmaxf(sqrtf(v2), EPS_F);
  float lamx = 2.f / fmaxf(1.f - x2, EPS_F);
  float s = tanhf(0.5f * lamx * vn) / vn;
  float xy = s * xv;
  float y2 = s * s * v2;
  float a  = 1.f + 2.f * xy + y2;
  float bb = 1.f - x2;
  float den = fmaxf(1.f + 2.f * xy + x2 * y2, EPS_F);
  float inv = 1.f / den;
  float4 res;
  res.x = (a * x.x + bb * s * v.x) * inv;
  res.y = (a * x.y + bb * s * v.y) * inv;
  res.z = (a * x.z + bb * s * v.z) * inv;
  res.w = (a * x.w + bb * s * v.w) * inv;
  float r2 = wave_sum(res.x * res.x + res.y * res.y + res.z * res.z + res.w * res.w);
  float rn = sqrtf(r2);
  if (rn > MAX_NORM_F) {
    float sc = MAX_NORM_F / fmaxf(rn, EPS_F);
    res.x *= sc; res.y *= sc; res.z *= sc; res.w *= sc;
    r2 = MAX_NORM_F * MAX_NORM_F;
    rn = MAX_NORM_F;
  }
  *reinterpret_cast<float4*>(zr + (size_t)(t + 30) * 256 + lane * 4) = res;

  if (t < 7) {
    float4 pm = pair_log(zr, t, lane);
    float xyn = wave_sum(x.x * res.x + x.y * res.y + x.z * res.z + x.w * res.w);
    float an  = 1.f - 2.f * xyn + r2;
    float bbn = 1.f - x2;
    float denn = fmaxf(1.f - 2.f * xyn + x2 * r2, EPS_F);
    float invn = 1.f / denn;
    float4 u;
    u.x = (bbn * res.x - an * x.x) * invn;
    u.y = (bbn * res.y - an * x.y) * invn;
    u.z = (bbn * res.z - an * x.z) * invn;
    u.w = (bbn * res.w - an * x.w) * invn;
    float u2 = wave_sum(u.x * u.x + u.y * u.y + u.z * u.z + u.w * u.w);
    float un = fmaxf(sqrtf(u2), EPS_F);
    float coef = fmaxf(1.f - x2, EPS_F) * atanhf(fminf(un, 1.f - 1e-7f)) / un;
    float4 vs = *reinterpret_cast<const float4*>(VSUM + (size_t)r * 256 + lane * 4);
    vs.x += coef * u.x - pm.x; vs.y += coef * u.y - pm.y;
    vs.z += coef * u.z - pm.z; vs.w += coef * u.w - pm.w;
    *reinterpret_cast<float4*>(VSUM + (size_t)r * 256 + lane * 4) = vs;

    float rnp = fmaxf(rn, EPS_F);
    float cl = atanhf(fminf(rnp, 1.f - 1e-7f)) / rnp;
    float nx = fmaxf(sqrtf(x2), EPS_F);
    float cp = atanhf(fminf(nx, 1.f - 1e-7f)) / nx;
    const size_t fb = (size_t)r * 768 + lane * 4;
    float4 o;
    o.x = cl * res.x; o.y = cl * res.y; o.z = cl * res.z; o.w = cl * res.w;
    store_hi4(Fh, fb, o);
    o.x = cp * x.x; o.y = cp * x.y; o.z = cp * x.z; o.w = cp * x.w;
    store_hi4(Fh, fb + 256, o);
    const float s29 = 1.f / 29.f;
    o.x = vs.x * s29; o.y = vs.y * s29; o.z = vs.z * s29; o.w = vs.w * s29;
    store_hi4(Fh, fb + 512, o);
  }
}

// -------------------------- logmap0 over appended cols, bf16-hi out
__global__ __launch_bounds__(256) void logmap0_rows_k(
    const float* __restrict__ Z, unsigned short* __restrict__ Uh)
{
  const int q = blockIdx.x * 4 + (threadIdx.x >> 6);
  const int lane = threadIdx.x & 63;
  const int r = q >> 3;
  const int tt = q & 7;
  float4 o = logmap0_col(Z + (size_t)r * 38 * 256, 30 + tt, lane);
  store_hi4(Uh, (size_t)q * 256 + lane * 4, o);
}

// ---------------------------------------------------------------- launcher
extern "C" void kernel_launch(void* const* d_in, const int* in_sizes, int n_in,
                              void* d_out, int out_size, void* d_ws, size_t ws_size,
                              hipStream_t stream)
{
  const float* c0 = (const float*)d_in[0];
  const float* c1 = (const float*)d_in[1];
  const float* c2 = (const float*)d_in[2];
  const float* c3 = (const float*)d_in[3];
  const float* W_embed = (const float*)d_in[4];
  const float* b_embed = (const float*)d_in[5];
  const float* ln_g    = (const float*)d_in[6];
  const float* ln_b    = (const float*)d_in[7];
  const float* W1 = (const float*)d_in[8];
  const float* b1 = (const float*)d_in[9];
  const float* W2 = (const float*)d_in[10];
  const float* b2 = (const float*)d_in[11];
  const float* W3 = (const float*)d_in[12];
  const float* b3 = (const float*)d_in[13];
  const float* W_out = (const float*)d_in[14];
  const float* b_out = (const float*)d_in[15];
  float* out = (float*)d_out;
  float* ws  = (float*)d_ws;

  // ---- ws layout. Peak identical to R10 (proven).
  float* Z = ws;
  unsigned short* Abf = (unsigned short*)ws;        // [61440][512] bf16 (aliases Z)
  unsigned short* Rs = (unsigned short*)(ws + 24903680u);
  unsigned short* TAN = Rs + 20000000u;             // 4*15360*256 shorts
  unsigned short* W1h = Rs;                         // [1024][768]
  unsigned short* W1l = Rs + 786432u;
  unsigned short* W2h = Rs + 1572864u;              // [1024][1024]
  unsigned short* W2l = Rs + 2621440u;
  unsigned short* W3h = Rs + 3670016u;              // [256][1024]
  unsigned short* W3l = Rs + 3932160u;
  unsigned short* Woh = Rs + 4194304u;              // [504][256]
  unsigned short* Wol = Rs + 4323328u;
  unsigned short* FEATh = Rs + 4452352u;            // [2560][768]
  unsigned short* H1h = Rs + 6418432u;              // [2560][1024]
  unsigned short* H2h = Rs + 9039872u;              // [2560][1024]
  unsigned short* Uh  = Rs + 11661312u;             // [20480][256] (stage C)
  float* VP   = ws + 34338816u;                     // 4 x 2560*256 parts
  float* VSUM = ws + 39581696u;                     // 2560*256

  unsigned short* EW = (unsigned short*)d_out;      // embed weights scratch

  dim3 blk(256);

  // Stage A: A->bf16 pre-pass + embed weight split -> embed GEMM -> LN
  c2bf_k<<<dim3(15360), blk, 0, stream>>>(c0, c1, c2, c3, Abf);
  {
    WS4 d;
    for (int c = 0; c < 4; ++c) {
      d.W[c] = W_embed + (size_t)c * 504 * 256;
      d.Th[c] = EW + (size_t)c * 262144u;
      d.Tl[c] = EW + (size_t)c * 262144u + 131072u;
      d.K[c] = 504; d.N[c] = 256; d.Kp[c] = 512;
    }
    wsplit_all_k<<<dim3(4, 8, 4), blk, 0, stream>>>(d);
  }
  gemm_embed1<<<dim3(480, 2), blk, 0, stream>>>(Abf, EW, b_embed, TAN);
  ln_expmap0_k<<<dim3(3840), blk, 0, stream>>>(TAN, ln_g, ln_b, Z);

  // MLP/out weight splits in one launch
  {
    WS4 d;
    d.W[0] = W1;    d.Th[0] = W1h; d.Tl[0] = W1l; d.K[0] = 768;  d.N[0] = 1024; d.Kp[0] = 768;
    d.W[1] = W2;    d.Th[1] = W2h; d.Tl[1] = W2l; d.K[1] = 1024; d.N[1] = 1024; d.Kp[1] = 1024;
    d.W[2] = W3;    d.Th[2] = W3h; d.Tl[2] = W3l; d.K[2] = 1024; d.N[2] = 256;  d.Kp[2] = 1024;
    d.W[3] = W_out; d.Th[3] = Woh; d.Tl[3] = Wol; d.K[3] = 256;  d.N[3] = 504;  d.Kp[3] = 256;
    wsplit_all_k<<<dim3(16, 16, 4), blk, 0, stream>>>(d);
  }

  // Stage B: 8 recurrent steps (x1 MLP weights; velocity/feat fused)
  vel_feat_t0_k<<<dim3(2560), blk, 0, stream>>>(Z, FEATh, VSUM);
  for (int t = 0; t < 8; ++t) {
    gemm_n64_x1<<<dim3(20, 16, 1), blk, 0, stream>>>(
        FEATh, 768, W1h, 768, b1, nullptr, H1h,
        1024, 2560, 1024, 768, 768, 1);
    gemm_n64_x1<<<dim3(20, 16, 1), blk, 0, stream>>>(
        H1h, 1024, W2h, 1024, b2, nullptr, H2h,
        1024, 2560, 1024, 1024, 1024, 1);
    gemm_n64_x1<<<dim3(20, 4, 4), blk, 0, stream>>>(
        H2h, 1024, W3h, 1024, nullptr, VP, nullptr,
        256, 2560, 256, 1024, 256, 0);
    expmap_vel_fused_k<<<dim3(640), blk, 0, stream>>>(
        Z, VP, b3, FEATh, VSUM, t);
  }

  // Stage C: logmap0 -> final projection into d_out (W_out stays x2)
  logmap0_rows_k<<<dim3(5120), blk, 0, stream>>>(Z, Uh);
  gemm_n64_x2<<<dim3(160, 8, 1), blk, 0, stream>>>(
      Uh, 256, Woh, Wol, 256, b_out, out, nullptr,
      504, 20480, 504, 256, 256, 0);
}